// Round 5
// baseline (1559.477 us; speedup 1.0000x reference)
//
#include <hip/hip_runtime.h>

// ---------------------------------------------------------------------------
// MRT12 v5: fp16-single GEMMs, BK=32 double-buffered (32KB LDS -> 5 blocks/CU
// for wave-level overlap, m114), linear LDS (contiguous 1KB fragment reads =
// conflict-free, no swizzle), global_load_lds width=16. Fused scan+conv.
// B=2,S=1024,D=1024,L=8,V=32000. fp32 in/out.
// ---------------------------------------------------------------------------

using short8 = __attribute__((ext_vector_type(8))) short;
using half8  = __attribute__((ext_vector_type(8))) _Float16;
using f32x4  = __attribute__((ext_vector_type(4))) float;

#define DEVI __device__ __forceinline__

DEVI float sigm(float x) { return 1.0f / (1.0f + expf(-x)); }

DEVI float block_sum256(float v) {
  #pragma unroll
  for (int o = 32; o > 0; o >>= 1) v += __shfl_down(v, o, 64);
  __shared__ float sm[4];
  if ((threadIdx.x & 63) == 0) sm[threadIdx.x >> 6] = v;
  __syncthreads();
  float t = sm[0] + sm[1] + sm[2] + sm[3];
  __syncthreads();
  return t;
}

DEVI void gload16(const void* g, void* l) {    // async global->LDS, 16B/lane
  __builtin_amdgcn_global_load_lds(
      (const __attribute__((address_space(1))) unsigned*)g,
      (__attribute__((address_space(3))) unsigned*)l, 16, 0, 0);
}

// ---------------------------------------------------------------------------
// GEMM v5: C[M,N] = A[M,K] * B[N,K]^T, fp16 MFMA. 128x128 tile, BK=32,
// 4 waves, 2-phase dbuf, 32KB LDS. Linear [128][32] LDS; fragment reads are
// contiguous 1KB per wave -> bank-conflict-free.
// EPI: 0 head (fp32 C + fused row stats); 1 keygen -> vaT[2D][M], tanh|sigm;
//      2 +bias, silu, fp16 out; 5 raw fp32 partial at outF + ks*M*N
// ---------------------------------------------------------------------------
template<int EPI, int KSPLIT>
__global__ __launch_bounds__(256, 5) void gemm5(
    const _Float16* __restrict__ A, const _Float16* __restrict__ B,
    int M, int N, int K,
    float* __restrict__ outF, _Float16* __restrict__ outH,
    const float* __restrict__ bias,
    float* __restrict__ psum, float* __restrict__ psq, int halfN)
{
  __shared__ __align__(16) unsigned short lds[2][2][128 * 32];
  const int tid  = threadIdx.x;
  const int lane = tid & 63, wid = tid >> 6;
  const int wr = wid >> 1, wc = wid & 1;

  // XCD-chunked swizzle (nwg % 8 == 0 for all launches), m-fastest decode
  const int nwg  = gridDim.x;
  const int flat = blockIdx.x;
  const int swz  = (flat & 7) * (nwg >> 3) + (flat >> 3);
  const int ks   = (KSPLIT > 1) ? (swz % KSPLIT) : 0;
  const int tile = (KSPLIT > 1) ? (swz / KSPLIT) : swz;
  const int MT   = M >> 7;
  const int m0   = (tile % MT) * 128;
  const int nt   = tile / MT;
  const int n0   = nt * 128;
  const int Kc   = K / KSPLIT;
  const int kbase = ks * Kc;
  const int NT   = Kc / 32;

  const int srow = lane >> 2;            // staging: row within 16-row group
  const int scol = (lane & 3) * 8;       // staging col (elements)

  auto stage = [&](int b, int k0) {
    #pragma unroll
    for (int q = 0; q < 2; ++q) {
      const int row = wid * 32 + q * 16 + srow;
      const size_t ga = (size_t)(m0 + row) * K + k0 + scol;
      const size_t gb = (size_t)(n0 + row) * K + k0 + scol;
      const int lo = wid * 1024 + q * 512;     // ushort offset, wave-uniform
      gload16(A + ga, &lds[b][0][lo]);
      gload16(B + gb, &lds[b][1][lo]);
    }
  };

  f32x4 acc[4][4] = {};
  const int myr = lane & 15;
  const int kq  = lane >> 4;             // k-quad 0..3 (8-elem slot)

  stage(0, kbase);
  __syncthreads();
  int cur = 0;
  for (int t = 0; t < NT; ++t) {
    if (t + 1 < NT) stage(cur ^ 1, kbase + (t + 1) * 32);
    short8 af[4], bfr[4];
    #pragma unroll
    for (int i = 0; i < 4; ++i) {
      const int ra = wr * 64 + i * 16 + myr;
      af[i] = *(const short8*)&lds[cur][0][ra * 32 + kq * 8];
      const int rb = wc * 64 + i * 16 + myr;
      bfr[i] = *(const short8*)&lds[cur][1][rb * 32 + kq * 8];
    }
    #pragma unroll
    for (int i = 0; i < 4; ++i)
      #pragma unroll
      for (int j = 0; j < 4; ++j)
        acc[i][j] = __builtin_amdgcn_mfma_f32_16x16x32_f16(
            __builtin_bit_cast(half8, af[i]), __builtin_bit_cast(half8, bfr[j]),
            acc[i][j], 0, 0, 0);
    __syncthreads();                     // reads done + prefetch drained
    cur ^= 1;
  }

  // epilogue: C/D frag row=(lane>>4)*4+r, col=lane&15 (m89)
  const size_t MN = (size_t)M * N;
  #pragma unroll
  for (int i = 0; i < 4; ++i) {
    const int rbase = m0 + wr * 64 + i * 16 + (kq << 2);
    #pragma unroll
    for (int j = 0; j < 4; ++j) {
      const int col = n0 + wc * 64 + j * 16 + myr;
      if constexpr (EPI == 1) {                    // channel-major vaT[col][row]
        f32x4 v;
        #pragma unroll
        for (int r = 0; r < 4; ++r) {
          float c = acc[i][j][r];
          v[r] = (col < halfN) ? (tanhf(c) * 3.14159265358979323846f) : sigm(c);
        }
        *(f32x4*)&outF[(size_t)col * M + rbase] = v;
      } else {
        #pragma unroll
        for (int r = 0; r < 4; ++r) {
          float c = acc[i][j][r];
          const size_t idx = (size_t)(rbase + r) * N + col;
          if constexpr (EPI == 0) {
            outF[idx] = c;
          } else if constexpr (EPI == 2) {
            c += bias[col];
            outH[idx] = (_Float16)(c * sigm(c));   // silu
          } else if constexpr (EPI == 5) {
            outF[(size_t)ks * MN + idx] = c;
          }
        }
      }
    }
  }

  if constexpr (EPI == 0) {                        // fused row stats (head)
    const int PW = N >> 6;
    const int pcol = nt * 2 + wc;
    #pragma unroll
    for (int i = 0; i < 4; ++i)
      #pragma unroll
      for (int r = 0; r < 4; ++r) {
        float s = 0.f, ss = 0.f;
        #pragma unroll
        for (int j = 0; j < 4; ++j) {
          float v = acc[i][j][r];
          s += v; ss += v * v;
        }
        #pragma unroll
        for (int mk = 1; mk < 16; mk <<= 1) {
          s  += __shfl_xor(s,  mk, 64);
          ss += __shfl_xor(ss, mk, 64);
        }
        if (myr == i * 4 + r) {
          const int row = m0 + wr * 64 + i * 16 + kq * 4 + r;
          psum[(size_t)row * PW + pcol] = s;
          psq [(size_t)row * PW + pcol] = ss;
        }
      }
  }
}

// ---------------------------------------------------------------------------
// Fused lerp-scan + causal dwconv3. vaT[2D][M] channel-major.
// 8 channels x 32 chunks of 32 steps per block.
// ---------------------------------------------------------------------------
__global__ __launch_bounds__(256) void scanconv(
    const float* __restrict__ vaT, const float* __restrict__ cw,
    const float* __restrict__ cb, _Float16* __restrict__ z16,
    int S, int D, int M)
{
  const int dl = threadIdx.x & 7;                // channel in block
  const int c  = threadIdx.x >> 3;               // chunk 0..31
  const int ch = blockIdx.x * 8 + dl;
  const int b = ch >> 10, d = ch & 1023;
  const int CH = S / 32;                         // 32
  const float* vrow = vaT + (size_t)d * M + b * S;
  const float* arow = vaT + (size_t)(D + d) * M + b * S;
  const int s0 = c * CH;

  float A = 1.f, Bv = 0.f, Apm = 1.f, Bpm = 0.f;
  for (int t = 0; t < CH; t += 4) {
    f32x4 v4 = *(const f32x4*)&vrow[s0 + t];
    f32x4 a4 = *(const f32x4*)&arow[s0 + t];
    #pragma unroll
    for (int r = 0; r < 4; ++r) {
      if (t + r == CH - 1) { Apm = A; Bpm = Bv; }
      float na = 1.f - a4[r];
      A *= na;
      Bv = Bv * na + a4[r] * v4[r];
    }
  }
  __shared__ float Asm[32][9], Bsm[32][9], Aps[32][9], Bps[32][9];
  Asm[c][dl] = A; Bsm[c][dl] = Bv; Aps[c][dl] = Apm; Bps[c][dl] = Bpm;
  __syncthreads();
  if (threadIdx.x < 8) {                         // serial exclusive prefix
    float run = 0.f;
    for (int cc = 0; cc < 32; ++cc) {
      float A_ = Asm[cc][dl], B_ = Bsm[cc][dl];
      Bsm[cc][dl] = run;                         // h before chunk cc
      run = A_ * run + B_;
    }
  }
  __syncthreads();
  float hm1 = Bsm[c][dl];
  float hm2 = (c == 0) ? 0.f
            : (Aps[c - 1][dl] * Bsm[c - 1][dl] + Bps[c - 1][dl]);

  const float w0 = cw[d * 3 + 0], w1 = cw[d * 3 + 1], w2 = cw[d * 3 + 2];
  const float bc = cb[d];
  for (int t = 0; t < CH; t += 4) {
    f32x4 v4 = *(const f32x4*)&vrow[s0 + t];
    f32x4 a4 = *(const f32x4*)&arow[s0 + t];
    #pragma unroll
    for (int r = 0; r < 4; ++r) {
      float h = hm1 + a4[r] * (v4[r] - hm1);
      float z = h + bc + w0 * hm2 + w1 * hm1 + w2 * h;
      z16[(size_t)(b * S + s0 + t + r) * D + d] = (_Float16)z;
      hm2 = hm1; hm1 = h;
    }
  }
}

// v = p0+p1+bias; delta = rmsnorm(v)*nw; x += delta; o16 = fp16(mode?delta:x)
__global__ __launch_bounds__(256) void rms_fuse(
    const float* __restrict__ p, const float* __restrict__ bias,
    const float* __restrict__ nw, float* __restrict__ x,
    _Float16* __restrict__ o16, int D, int mode, size_t MN)
{
  const size_t base = (size_t)blockIdx.x * D;
  float vloc[4]; float ss = 0.f;
  #pragma unroll
  for (int q = 0; q < 4; ++q) {
    int d = threadIdx.x + q * 256;
    float v = p[base + d] + p[MN + base + d] + bias[d];
    vloc[q] = v; ss += v * v;
  }
  ss = block_sum256(ss);
  float r = 1.f / sqrtf(ss / D + 1e-8f);
  #pragma unroll
  for (int q = 0; q < 4; ++q) {
    int d = threadIdx.x + q * 256;
    float delta = vloc[q] * r * nw[d];
    float xn = x[base + d] + delta;
    x[base + d] = xn;
    o16[base + d] = (_Float16)(mode ? delta : xn);
  }
}

// x += p0+p1 (split-K partials of delta@plastic); x16 = fp16(x)
__global__ __launch_bounds__(256) void xupd(
    const float* __restrict__ p, float* __restrict__ x,
    _Float16* __restrict__ x16, size_t MN)
{
  size_t i = (size_t)blockIdx.x * 256 + threadIdx.x;
  if (i >= MN) return;
  float xn = x[i] + p[i] + p[MN + i];
  x[i] = xn;
  x16[i] = (_Float16)xn;
}

__global__ __launch_bounds__(256) void embed_norm(
    const int* __restrict__ ids, const float* __restrict__ emb,
    const float* __restrict__ pos,
    float* __restrict__ x, _Float16* __restrict__ x16, int S, int D)
{
  const int rowi = blockIdx.x;
  const int s = rowi % S;
  const int tok = ids[rowi];
  const size_t eb = (size_t)tok * D, pb = (size_t)s * D, xb = (size_t)rowi * D;
  float vloc[4]; float ss = 0.f;
  #pragma unroll
  for (int q = 0; q < 4; ++q) {
    int d = threadIdx.x + q * 256;
    float v = emb[eb + d] + pos[pb + d];
    vloc[q] = v; ss += v * v;
  }
  ss = block_sum256(ss);
  float r = 1.f / fmaxf(sqrtf(ss), 1e-12f);
  #pragma unroll
  for (int q = 0; q < 4; ++q) {
    int d = threadIdx.x + q * 256;
    float v = vloc[q] * r;
    x[xb + d] = v;
    x16[xb + d] = (_Float16)v;
  }
}

__global__ __launch_bounds__(256) void final_norm(
    const float* __restrict__ x, const float* __restrict__ w,
    _Float16* __restrict__ xf, int D)
{
  const size_t base = (size_t)blockIdx.x * D;
  float s1 = 0.f, s2 = 0.f;
  float vloc[4], wloc[4];
  #pragma unroll
  for (int q = 0; q < 4; ++q) {
    int d = threadIdx.x + q * 256;
    float v = x[base + d], ww = w[d];
    vloc[q] = v; wloc[q] = ww;
    s1 += v * v; s2 += v * ww * v * ww;
  }
  s1 = block_sum256(s1);
  s2 = block_sum256(s2);
  float r1 = 1.f / sqrtf(s1 / D + 1e-8f);
  float m2 = r1 * r1 * (s2 / D);
  float r2 = 1.f / sqrtf(m2 + 1e-8f);
  float sc = r1 * r2 * 0.8f;
  #pragma unroll
  for (int q = 0; q < 4; ++q) {
    int d = threadIdx.x + q * 256;
    xf[base + d] = (_Float16)(vloc[q] * wloc[q] * sc);
  }
}

__global__ __launch_bounds__(256) void reduce_scale(
    const float* __restrict__ psum, const float* __restrict__ psq,
    float* __restrict__ scale, int PW, int V)
{
  const int row = blockIdx.x;
  float s = 0.f, q = 0.f;
  for (int j = threadIdx.x; j < PW; j += 256) {
    s += psum[(size_t)row * PW + j];
    q += psq [(size_t)row * PW + j];
  }
  s = block_sum256(s);
  q = block_sum256(q);
  float mean = s / V;
  float var = (q - (float)V * mean * mean) / (float)(V - 1);
  var = fmaxf(var, 0.f);
  if (threadIdx.x == 0) scale[row] = 1.f / fmaxf(sqrtf(var), 1.f);
}

__global__ __launch_bounds__(256) void fix_apply(
    float* __restrict__ out, const float* __restrict__ scale, int V)
{
  const int row = blockIdx.y;
  const int j = (blockIdx.x * 256 + threadIdx.x) * 4;
  if (j >= V) return;
  const float sc = scale[row];
  f32x4 v = *(f32x4*)&out[(size_t)row * V + j];
  #pragma unroll
  for (int t = 0; t < 4; ++t)
    v[t] = fminf(fmaxf(v[t] * sc, -10.f), 10.f);
  *(f32x4*)&out[(size_t)row * V + j] = v;
}

// W[K,N] fp32 -> WT[N,K] fp16 (transposed), batched over blockIdx.z
__global__ void tsplit16(const float* __restrict__ W, _Float16* __restrict__ WT,
                         int K, int N)
{
  __shared__ float t[32][33];
  const size_t bo = (size_t)blockIdx.z * K * N;
  const int tx = threadIdx.x, ty = threadIdx.y;
  #pragma unroll
  for (int i = 0; i < 32; i += 8) {
    int kk = blockIdx.y * 32 + ty + i;
    int nn = blockIdx.x * 32 + tx;
    t[ty + i][tx] = W[bo + (size_t)kk * N + nn];
  }
  __syncthreads();
  #pragma unroll
  for (int i = 0; i < 32; i += 8) {
    int nn = blockIdx.x * 32 + ty + i;
    int kk = blockIdx.y * 32 + tx;
    WT[bo + (size_t)nn * K + kk] = (_Float16)t[tx][ty + i];
  }
}

__global__ void cvt_f16(const float* __restrict__ in, _Float16* __restrict__ o, size_t n)
{
  for (size_t i = (size_t)blockIdx.x * 256 + threadIdx.x; i < n;
       i += (size_t)gridDim.x * 256)
    o[i] = (_Float16)in[i];
}

// ---------------------------------------------------------------------------
extern "C" void kernel_launch(void* const* d_in, const int* in_sizes, int n_in,
                              void* d_out, int out_size, void* d_ws, size_t ws_size,
                              hipStream_t stream)
{
  (void)in_sizes; (void)n_in; (void)out_size; (void)ws_size;
  const int*   ids = (const int*)  d_in[0];
  const float* emb = (const float*)d_in[1];
  const float* pos = (const float*)d_in[2];
  const float* kw  = (const float*)d_in[3];
  const float* cw  = (const float*)d_in[4];
  const float* cb  = (const float*)d_in[5];
  const float* w1  = (const float*)d_in[6];
  const float* b1  = (const float*)d_in[7];
  const float* w2  = (const float*)d_in[8];
  const float* b2  = (const float*)d_in[9];
  const float* nw  = (const float*)d_in[10];
  const float* pl  = (const float*)d_in[11];
  const float* fnw = (const float*)d_in[12];
  float* out = (float*)d_out;

  constexpr int B = 2, S = 1024, D = 1024, L = 8, V = 32000;
  constexpr int M = B * S;
  const size_t MN = (size_t)M * D;

  size_t off = 0;
  auto alloc = [&](size_t bytes) {
    char* p = (char*)d_ws + off;
    off += (bytes + 255) & ~(size_t)255;
    return (void*)p;
  };
  _Float16* kwT  = (_Float16*)alloc((size_t)L * 2 * D * D * 2);
  _Float16* w1T  = (_Float16*)alloc((size_t)L * 2 * D * D * 2);
  _Float16* w2T  = (_Float16*)alloc((size_t)L * 2 * D * D * 2);
  _Float16* plT  = (_Float16*)alloc((size_t)4 * D * D * 2);
  _Float16* emb16 = (_Float16*)alloc((size_t)V * D * 2);
  float* x    = (float*)alloc(MN * 4);
  _Float16* x16 = (_Float16*)alloc(MN * 2);
  float* vaT  = (float*)alloc((size_t)M * 2 * D * 4);   // [2D][M]
  float* pbuf = (float*)alloc(2 * MN * 4);              // split-K partials
  _Float16* z16 = (_Float16*)alloc(MN * 2);
  _Float16* u16 = (_Float16*)alloc((size_t)M * 2 * D * 2);
  _Float16* d16 = (_Float16*)alloc(MN * 2);
  _Float16* xf16 = (_Float16*)alloc(MN * 2);

  // head stats overlay vaT (free at head time): PW = V/64 = 500
  const int PW = V >> 6;
  float* psum  = vaT;
  float* psq   = vaT + (size_t)M * PW;
  float* scale = psq + (size_t)M * PW;

  // ---- weight prep ----
  {
    dim3 tb(32, 8);
    tsplit16<<<dim3(2 * D / 32, D / 32, L), tb, 0, stream>>>(kw, kwT, D, 2 * D);
    tsplit16<<<dim3(2 * D / 32, D / 32, L), tb, 0, stream>>>(w1, w1T, D, 2 * D);
    tsplit16<<<dim3(D / 32, 2 * D / 32, L), tb, 0, stream>>>(w2, w2T, 2 * D, D);
    tsplit16<<<dim3(D / 32, D / 32, 4),     tb, 0, stream>>>(pl, plT, D, D);
    cvt_f16<<<4096, 256, 0, stream>>>(emb, emb16, (size_t)V * D);
  }

  embed_norm<<<M, 256, 0, stream>>>(ids, emb, pos, x, x16, S, D);

  for (int i = 0; i < L; ++i) {
    const _Float16* kwi = kwT + (size_t)i * 2 * D * D;
    const _Float16* w1i = w1T + (size_t)i * 2 * D * D;
    const _Float16* w2i = w2T + (size_t)i * 2 * D * D;

    // G1: res = x@kw -> vaT channel-major, v=tanh*pi | a=sigmoid
    gemm5<1, 1><<<(M / 128) * (2 * D / 128), 256, 0, stream>>>(
        x16, kwi, M, 2 * D, D, vaT, nullptr, nullptr, nullptr, nullptr, D);

    scanconv<<<B * D / 8, 256, 0, stream>>>(
        vaT, cw + (size_t)i * D * 3, cb + (size_t)i * D, z16, S, D, M);

    // G2: u = silu(z@w1 + b1) -> fp16
    gemm5<2, 1><<<(M / 128) * (2 * D / 128), 256, 0, stream>>>(
        z16, w1i, M, 2 * D, D, nullptr, u16, b1 + (size_t)i * 2 * D,
        nullptr, nullptr, 0);

    // G3: hf partials = u@w2 (split-K x2)
    gemm5<5, 2><<<(M / 128) * (D / 128) * 2, 256, 0, stream>>>(
        u16, w2i, M, D, 2 * D, pbuf, nullptr, nullptr, nullptr, nullptr, 0);

    const int mode = (i >= L - 4) ? 1 : 0;
    rms_fuse<<<M, 256, 0, stream>>>(pbuf, b2 + (size_t)i * D, nw + (size_t)i * D,
                                    x, mode ? d16 : x16, D, mode, MN);
    if (mode) {
      const _Float16* pli = plT + (size_t)(i - 4) * D * D;
      // G4: partials = delta @ plastic (split-K x2)
      gemm5<5, 2><<<(M / 128) * (D / 128) * 2, 256, 0, stream>>>(
          d16, pli, M, D, D, pbuf, nullptr, nullptr, nullptr, nullptr, 0);
      xupd<<<(int)(MN / 256), 256, 0, stream>>>(pbuf, x, x16, MN);
    }
  }

  final_norm<<<M, 256, 0, stream>>>(x, fnw, xf16, D);

  // LM head: logits = xf @ emb^T + fused row stats
  gemm5<0, 1><<<(M / 128) * (V / 128), 256, 0, stream>>>(
      xf16, emb16, M, V, D, out, nullptr, nullptr, psum, psq, 0);

  reduce_scale<<<M, 256, 0, stream>>>(psum, psq, scale, PW, V);
  fix_apply<<<dim3((V / 4 + 255) / 256, M), 256, 0, stream>>>(out, scale, V);
}

// Round 6
// 1399.749 us; speedup vs baseline: 1.1141x; 1.1141x over previous
//
#include <hip/hip_runtime.h>

// ---------------------------------------------------------------------------
// MRT12 v6: fp16 GEMMs with depth-3 software pipeline (3 LDS buffers, counted
// s_waitcnt vmcnt(4), single barrier per k-step) — targets 1-block/CU layer
// GEMMs where cross-block overlap is absent. G1 split-K x2 with combine fused
// into a register-cached scan+conv. Head: fused row stats; fix fused per-row.
// B=2,S=1024,D=1024,L=8,V=32000. fp32 in/out.
// ---------------------------------------------------------------------------

using short8 = __attribute__((ext_vector_type(8))) short;
using half8  = __attribute__((ext_vector_type(8))) _Float16;
using f32x4  = __attribute__((ext_vector_type(4))) float;

#define DEVI __device__ __forceinline__

DEVI float sigm(float x) { return 1.0f / (1.0f + expf(-x)); }

DEVI float block_sum256(float v) {
  #pragma unroll
  for (int o = 32; o > 0; o >>= 1) v += __shfl_down(v, o, 64);
  __shared__ float sm[4];
  if ((threadIdx.x & 63) == 0) sm[threadIdx.x >> 6] = v;
  __syncthreads();
  float t = sm[0] + sm[1] + sm[2] + sm[3];
  __syncthreads();
  return t;
}

DEVI void gload16(const void* g, void* l) {    // async global->LDS, 16B/lane
  __builtin_amdgcn_global_load_lds(
      (const __attribute__((address_space(1))) unsigned*)g,
      (__attribute__((address_space(3))) unsigned*)l, 16, 0, 0);
}

// ---------------------------------------------------------------------------
// GEMM v6: C[M,N] = A[M,K] * B[N,K]^T, fp16 MFMA. 128x128 tile, BK=32,
// 4 waves, DEPTH-3 pipeline: prologue stages tiles 0,1; per iter:
//   vmcnt(4) [tile-t loads landed] -> s_barrier -> stage(t+2) -> ds_read(t)
//   -> 16 MFMA. vmcnt(0) on the final iter only.
// EPI: 0 head (fp32 C + fused row sum/sumsq partials)
//      2 +bias, silu, fp16 out [M][N]
//      5 raw fp32 partial at outF + ks*M*N           (split-K, row-major)
//      6 raw fp32 partial, channel-major outF[ks*M*N + col*M + row] (G1)
// ---------------------------------------------------------------------------
template<int EPI, int KSPLIT>
__global__ __launch_bounds__(256, 3) void gemm6(
    const _Float16* __restrict__ A, const _Float16* __restrict__ B,
    int M, int N, int K,
    float* __restrict__ outF, _Float16* __restrict__ outH,
    const float* __restrict__ bias,
    float* __restrict__ psum, float* __restrict__ psq)
{
  __shared__ __align__(16) unsigned short lds[3][2][128 * 32];
  const int tid  = threadIdx.x;
  const int lane = tid & 63, wid = tid >> 6;
  const int wr = wid >> 1, wc = wid & 1;

  // XCD-chunked swizzle (nwg % 8 == 0 for all launches), m-fastest decode
  const int nwg  = gridDim.x;
  const int flat = blockIdx.x;
  const int swz  = (flat & 7) * (nwg >> 3) + (flat >> 3);
  const int ks   = (KSPLIT > 1) ? (swz % KSPLIT) : 0;
  const int tile = (KSPLIT > 1) ? (swz / KSPLIT) : swz;
  const int MT   = M >> 7;
  const int m0   = (tile % MT) * 128;
  const int nt   = tile / MT;
  const int n0   = nt * 128;
  const int Kc   = K / KSPLIT;
  const int kbase = ks * Kc;
  const int NT   = Kc / 32;              // >= 2 always here

  const int srow = lane >> 2;            // staging row within 16-row group
  const int scol = (lane & 3) * 8;       // staging col (elements)

  auto stage = [&](int b, int k0) {
    #pragma unroll
    for (int q = 0; q < 2; ++q) {
      const int row = wid * 32 + q * 16 + srow;
      const size_t ga = (size_t)(m0 + row) * K + k0 + scol;
      const size_t gb = (size_t)(n0 + row) * K + k0 + scol;
      const int lo = wid * 1024 + q * 512;     // ushort offset, wave-uniform
      gload16(A + ga, &lds[b][0][lo]);
      gload16(B + gb, &lds[b][1][lo]);
    }
  };

  f32x4 acc[4][4] = {};
  const int myr = lane & 15;
  const int kq  = lane >> 4;             // k-quad 0..3 (8-elem slot)

  stage(0, kbase);
  stage(1, kbase + 32);
  int cur = 0, nxt = 2;
  for (int t = 0; t < NT; ++t) {
    if (t + 1 < NT) { asm volatile("s_waitcnt vmcnt(4)" ::: "memory"); }
    else            { asm volatile("s_waitcnt vmcnt(0)" ::: "memory"); }
    __builtin_amdgcn_s_barrier();        // tile t ready everywhere; buf nxt free
    if (t + 2 < NT) stage(nxt, kbase + (t + 2) * 32);

    short8 af[4], bfr[4];
    #pragma unroll
    for (int i = 0; i < 4; ++i) {
      const int ra = wr * 64 + i * 16 + myr;
      af[i] = *(const short8*)&lds[cur][0][ra * 32 + kq * 8];
      const int rb = wc * 64 + i * 16 + myr;
      bfr[i] = *(const short8*)&lds[cur][1][rb * 32 + kq * 8];
    }
    #pragma unroll
    for (int i = 0; i < 4; ++i)
      #pragma unroll
      for (int j = 0; j < 4; ++j)
        acc[i][j] = __builtin_amdgcn_mfma_f32_16x16x32_f16(
            __builtin_bit_cast(half8, af[i]), __builtin_bit_cast(half8, bfr[j]),
            acc[i][j], 0, 0, 0);
    cur = (cur == 2) ? 0 : cur + 1;
    nxt = (nxt == 2) ? 0 : nxt + 1;
  }

  // epilogue: C/D frag row=(lane>>4)*4+r, col=lane&15 (m89)
  const size_t MN = (size_t)M * N;
  #pragma unroll
  for (int i = 0; i < 4; ++i) {
    const int rbase = m0 + wr * 64 + i * 16 + (kq << 2);
    #pragma unroll
    for (int j = 0; j < 4; ++j) {
      const int col = n0 + wc * 64 + j * 16 + myr;
      if constexpr (EPI == 6) {          // channel-major partial [col][row]
        f32x4 v;
        #pragma unroll
        for (int r = 0; r < 4; ++r) v[r] = acc[i][j][r];
        *(f32x4*)&outF[(size_t)ks * MN + (size_t)col * M + rbase] = v;
      } else {
        #pragma unroll
        for (int r = 0; r < 4; ++r) {
          float c = acc[i][j][r];
          const size_t idx = (size_t)(rbase + r) * N + col;
          if constexpr (EPI == 0) {
            outF[idx] = c;
          } else if constexpr (EPI == 2) {
            c += bias[col];
            outH[idx] = (_Float16)(c * sigm(c));   // silu
          } else if constexpr (EPI == 5) {
            outF[(size_t)ks * MN + idx] = c;
          }
        }
      }
    }
  }

  if constexpr (EPI == 0) {                        // fused row stats (head)
    const int PW = N >> 6;
    const int pcol = nt * 2 + wc;
    #pragma unroll
    for (int i = 0; i < 4; ++i)
      #pragma unroll
      for (int r = 0; r < 4; ++r) {
        float s = 0.f, ss = 0.f;
        #pragma unroll
        for (int j = 0; j < 4; ++j) {
          float v = acc[i][j][r];
          s += v; ss += v * v;
        }
        #pragma unroll
        for (int mk = 1; mk < 16; mk <<= 1) {
          s  += __shfl_xor(s,  mk, 64);
          ss += __shfl_xor(ss, mk, 64);
        }
        if (myr == i * 4 + r) {
          const int row = m0 + wr * 64 + i * 16 + kq * 4 + r;
          psum[(size_t)row * PW + pcol] = s;
          psq [(size_t)row * PW + pcol] = ss;
        }
      }
  }
}

// ---------------------------------------------------------------------------
// Fused split-K combine + tanh/sigm + lerp-scan + causal dwconv3.
// Reads G1 partials channel-major pbig[ks][2D][M]; v,a computed ONCE and kept
// in registers for both scan passes. 8 channels x 32 chunks of 32 steps.
// ---------------------------------------------------------------------------
__global__ __launch_bounds__(256) void scanconv2(
    const float* __restrict__ pbig, const float* __restrict__ cw,
    const float* __restrict__ cb, _Float16* __restrict__ z16,
    int S, int D, int M)
{
  const int dl = threadIdx.x & 7;                // channel in block
  const int c  = threadIdx.x >> 3;               // chunk 0..31
  const int ch = blockIdx.x * 8 + dl;
  const int b = ch >> 10, d = ch & 1023;
  const int CH = S / 32;                         // 32
  const size_t P1 = (size_t)2 * D * M;
  const float* t0 = pbig + (size_t)d * M + b * S;
  const float* a0 = pbig + (size_t)(D + d) * M + b * S;
  const int s0 = c * CH;

  f32x4 vr[8], ar[8];
  float A = 1.f, Bv = 0.f, Apm = 1.f, Bpm = 0.f;
  #pragma unroll
  for (int t = 0; t < 8; ++t) {
    f32x4 th = *(const f32x4*)&t0[s0 + t * 4];
    f32x4 th2 = *(const f32x4*)&t0[P1 + s0 + t * 4];
    f32x4 aa = *(const f32x4*)&a0[s0 + t * 4];
    f32x4 aa2 = *(const f32x4*)&a0[P1 + s0 + t * 4];
    #pragma unroll
    for (int r = 0; r < 4; ++r) {
      float v = tanhf(th[r] + th2[r]) * 3.14159265358979323846f;
      float a = sigm(aa[r] + aa2[r]);
      vr[t][r] = v; ar[t][r] = a;
      if (t * 4 + r == CH - 1) { Apm = A; Bpm = Bv; }
      float na = 1.f - a;
      A *= na;
      Bv = Bv * na + a * v;
    }
  }
  __shared__ float Asm[32][9], Bsm[32][9], Aps[32][9], Bps[32][9];
  Asm[c][dl] = A; Bsm[c][dl] = Bv; Aps[c][dl] = Apm; Bps[c][dl] = Bpm;
  __syncthreads();
  if (threadIdx.x < 8) {                         // serial exclusive prefix
    float run = 0.f;
    for (int cc = 0; cc < 32; ++cc) {
      float A_ = Asm[cc][dl], B_ = Bsm[cc][dl];
      Bsm[cc][dl] = run;                         // h before chunk cc
      run = A_ * run + B_;
    }
  }
  __syncthreads();
  float hm1 = Bsm[c][dl];
  float hm2 = (c == 0) ? 0.f
            : (Aps[c - 1][dl] * Bsm[c - 1][dl] + Bps[c - 1][dl]);

  const float w0 = cw[d * 3 + 0], w1 = cw[d * 3 + 1], w2 = cw[d * 3 + 2];
  const float bc = cb[d];
  #pragma unroll
  for (int t = 0; t < 8; ++t) {
    #pragma unroll
    for (int r = 0; r < 4; ++r) {
      float h = hm1 + ar[t][r] * (vr[t][r] - hm1);
      float z = h + bc + w0 * hm2 + w1 * hm1 + w2 * h;
      z16[(size_t)(b * S + s0 + t * 4 + r) * D + d] = (_Float16)z;
      hm2 = hm1; hm1 = h;
    }
  }
}

// v = p0+p1+bias; delta = rmsnorm(v)*nw; x += delta; o16 = fp16(mode?delta:x)
__global__ __launch_bounds__(256) void rms_fuse(
    const float* __restrict__ p, const float* __restrict__ bias,
    const float* __restrict__ nw, float* __restrict__ x,
    _Float16* __restrict__ o16, int D, int mode, size_t MN)
{
  const size_t base = (size_t)blockIdx.x * D;
  float vloc[4]; float ss = 0.f;
  #pragma unroll
  for (int q = 0; q < 4; ++q) {
    int d = threadIdx.x + q * 256;
    float v = p[base + d] + p[MN + base + d] + bias[d];
    vloc[q] = v; ss += v * v;
  }
  ss = block_sum256(ss);
  float r = 1.f / sqrtf(ss / D + 1e-8f);
  #pragma unroll
  for (int q = 0; q < 4; ++q) {
    int d = threadIdx.x + q * 256;
    float delta = vloc[q] * r * nw[d];
    float xn = x[base + d] + delta;
    x[base + d] = xn;
    o16[base + d] = (_Float16)(mode ? delta : xn);
  }
}

// x += p0+p1 (split-K partials of delta@plastic); x16 = fp16(x)
__global__ __launch_bounds__(256) void xupd(
    const float* __restrict__ p, float* __restrict__ x,
    _Float16* __restrict__ x16, size_t MN)
{
  size_t i = (size_t)blockIdx.x * 256 + threadIdx.x;
  if (i >= MN) return;
  float xn = x[i] + p[i] + p[MN + i];
  x[i] = xn;
  x16[i] = (_Float16)xn;
}

__global__ __launch_bounds__(256) void embed_norm(
    const int* __restrict__ ids, const float* __restrict__ emb,
    const float* __restrict__ pos,
    float* __restrict__ x, _Float16* __restrict__ x16, int S, int D)
{
  const int rowi = blockIdx.x;
  const int s = rowi % S;
  const int tok = ids[rowi];
  const size_t eb = (size_t)tok * D, pb = (size_t)s * D, xb = (size_t)rowi * D;
  float vloc[4]; float ss = 0.f;
  #pragma unroll
  for (int q = 0; q < 4; ++q) {
    int d = threadIdx.x + q * 256;
    float v = emb[eb + d] + pos[pb + d];
    vloc[q] = v; ss += v * v;
  }
  ss = block_sum256(ss);
  float r = 1.f / fmaxf(sqrtf(ss), 1e-12f);
  #pragma unroll
  for (int q = 0; q < 4; ++q) {
    int d = threadIdx.x + q * 256;
    float v = vloc[q] * r;
    x[xb + d] = v;
    x16[xb + d] = (_Float16)v;
  }
}

__global__ __launch_bounds__(256) void final_norm(
    const float* __restrict__ x, const float* __restrict__ w,
    _Float16* __restrict__ xf, int D)
{
  const size_t base = (size_t)blockIdx.x * D;
  float s1 = 0.f, s2 = 0.f;
  float vloc[4], wloc[4];
  #pragma unroll
  for (int q = 0; q < 4; ++q) {
    int d = threadIdx.x + q * 256;
    float v = x[base + d], ww = w[d];
    vloc[q] = v; wloc[q] = ww;
    s1 += v * v; s2 += v * ww * v * ww;
  }
  s1 = block_sum256(s1);
  s2 = block_sum256(s2);
  float r1 = 1.f / sqrtf(s1 / D + 1e-8f);
  float m2 = r1 * r1 * (s2 / D);
  float r2 = 1.f / sqrtf(m2 + 1e-8f);
  float sc = r1 * r2 * 0.8f;
  #pragma unroll
  for (int q = 0; q < 4; ++q) {
    int d = threadIdx.x + q * 256;
    xf[base + d] = (_Float16)(vloc[q] * wloc[q] * sc);
  }
}

// fused: reduce partials -> scale = 1/max(std,1); then scale+clip the row
__global__ __launch_bounds__(256) void fix_row(
    float* __restrict__ out, const float* __restrict__ psum,
    const float* __restrict__ psq, int PW, int V)
{
  const int row = blockIdx.x;
  float s = 0.f, q = 0.f;
  for (int j = threadIdx.x; j < PW; j += 256) {
    s += psum[(size_t)row * PW + j];
    q += psq [(size_t)row * PW + j];
  }
  s = block_sum256(s);
  q = block_sum256(q);
  float mean = s / V;
  float var = (q - (float)V * mean * mean) / (float)(V - 1);
  var = fmaxf(var, 0.f);
  const float sc = 1.f / fmaxf(sqrtf(var), 1.f);
  float* rowp = out + (size_t)row * V;
  for (int j = threadIdx.x * 4; j < V; j += 1024) {
    f32x4 v = *(f32x4*)&rowp[j];
    #pragma unroll
    for (int t = 0; t < 4; ++t)
      v[t] = fminf(fmaxf(v[t] * sc, -10.f), 10.f);
    *(f32x4*)&rowp[j] = v;
  }
}

// W[K,N] fp32 -> WT[N,K] fp16 (transposed), batched over blockIdx.z
__global__ void tsplit16(const float* __restrict__ W, _Float16* __restrict__ WT,
                         int K, int N)
{
  __shared__ float t[32][33];
  const size_t bo = (size_t)blockIdx.z * K * N;
  const int tx = threadIdx.x, ty = threadIdx.y;
  #pragma unroll
  for (int i = 0; i < 32; i += 8) {
    int kk = blockIdx.y * 32 + ty + i;
    int nn = blockIdx.x * 32 + tx;
    t[ty + i][tx] = W[bo + (size_t)kk * N + nn];
  }
  __syncthreads();
  #pragma unroll
  for (int i = 0; i < 32; i += 8) {
    int nn = blockIdx.x * 32 + ty + i;
    int kk = blockIdx.y * 32 + tx;
    WT[bo + (size_t)nn * K + kk] = (_Float16)t[tx][ty + i];
  }
}

__global__ void cvt_f16(const float* __restrict__ in, _Float16* __restrict__ o, size_t n)
{
  for (size_t i = (size_t)blockIdx.x * 256 + threadIdx.x; i < n;
       i += (size_t)gridDim.x * 256)
    o[i] = (_Float16)in[i];
}

// ---------------------------------------------------------------------------
extern "C" void kernel_launch(void* const* d_in, const int* in_sizes, int n_in,
                              void* d_out, int out_size, void* d_ws, size_t ws_size,
                              hipStream_t stream)
{
  (void)in_sizes; (void)n_in; (void)out_size; (void)ws_size;
  const int*   ids = (const int*)  d_in[0];
  const float* emb = (const float*)d_in[1];
  const float* pos = (const float*)d_in[2];
  const float* kw  = (const float*)d_in[3];
  const float* cw  = (const float*)d_in[4];
  const float* cb  = (const float*)d_in[5];
  const float* w1  = (const float*)d_in[6];
  const float* b1  = (const float*)d_in[7];
  const float* w2  = (const float*)d_in[8];
  const float* b2  = (const float*)d_in[9];
  const float* nw  = (const float*)d_in[10];
  const float* pl  = (const float*)d_in[11];
  const float* fnw = (const float*)d_in[12];
  float* out = (float*)d_out;

  constexpr int B = 2, S = 1024, D = 1024, L = 8, V = 32000;
  constexpr int M = B * S;
  const size_t MN = (size_t)M * D;

  size_t off = 0;
  auto alloc = [&](size_t bytes) {
    char* p = (char*)d_ws + off;
    off += (bytes + 255) & ~(size_t)255;
    return (void*)p;
  };
  _Float16* kwT  = (_Float16*)alloc((size_t)L * 2 * D * D * 2);
  _Float16* w1T  = (_Float16*)alloc((size_t)L * 2 * D * D * 2);
  _Float16* w2T  = (_Float16*)alloc((size_t)L * 2 * D * D * 2);
  _Float16* plT  = (_Float16*)alloc((size_t)4 * D * D * 2);
  _Float16* emb16 = (_Float16*)alloc((size_t)V * D * 2);
  float* x    = (float*)alloc(MN * 4);
  _Float16* x16 = (_Float16*)alloc(MN * 2);
  float* pbig = (float*)alloc((size_t)2 * M * 2 * D * 4);  // 67 MB partials
  _Float16* z16 = (_Float16*)alloc(MN * 2);
  _Float16* u16 = (_Float16*)alloc((size_t)M * 2 * D * 2);
  _Float16* d16 = (_Float16*)alloc(MN * 2);
  _Float16* xf16 = (_Float16*)alloc(MN * 2);

  // head stats overlay pbig (free at head time): PW = V/64 = 500
  const int PW = V >> 6;
  float* psum = pbig;
  float* psq  = pbig + (size_t)M * PW;

  // ---- weight prep ----
  {
    dim3 tb(32, 8);
    tsplit16<<<dim3(2 * D / 32, D / 32, L), tb, 0, stream>>>(kw, kwT, D, 2 * D);
    tsplit16<<<dim3(2 * D / 32, D / 32, L), tb, 0, stream>>>(w1, w1T, D, 2 * D);
    tsplit16<<<dim3(D / 32, 2 * D / 32, L), tb, 0, stream>>>(w2, w2T, 2 * D, D);
    tsplit16<<<dim3(D / 32, D / 32, 4),     tb, 0, stream>>>(pl, plT, D, D);
    cvt_f16<<<4096, 256, 0, stream>>>(emb, emb16, (size_t)V * D);
  }

  embed_norm<<<M, 256, 0, stream>>>(ids, emb, pos, x, x16, S, D);

  for (int i = 0; i < L; ++i) {
    const _Float16* kwi = kwT + (size_t)i * 2 * D * D;
    const _Float16* w1i = w1T + (size_t)i * 2 * D * D;
    const _Float16* w2i = w2T + (size_t)i * 2 * D * D;

    // G1: partials = x@kw (split-K x2), channel-major [ks][2D][M]
    gemm6<6, 2><<<(M / 128) * (2 * D / 128) * 2, 256, 0, stream>>>(
        x16, kwi, M, 2 * D, D, pbig, nullptr, nullptr, nullptr, nullptr);

    // fused combine + tanh/sigm + scan + conv -> z16
    scanconv2<<<B * D / 8, 256, 0, stream>>>(
        pbig, cw + (size_t)i * D * 3, cb + (size_t)i * D, z16, S, D, M);

    // G2: u = silu(z@w1 + b1) -> fp16
    gemm6<2, 1><<<(M / 128) * (2 * D / 128), 256, 0, stream>>>(
        z16, w1i, M, 2 * D, D, nullptr, u16, b1 + (size_t)i * 2 * D,
        nullptr, nullptr);

    // G3: hf partials = u@w2 (split-K x2)
    gemm6<5, 2><<<(M / 128) * (D / 128) * 2, 256, 0, stream>>>(
        u16, w2i, M, D, 2 * D, pbig, nullptr, nullptr, nullptr, nullptr);

    const int mode = (i >= L - 4) ? 1 : 0;
    rms_fuse<<<M, 256, 0, stream>>>(pbig, b2 + (size_t)i * D, nw + (size_t)i * D,
                                    x, mode ? d16 : x16, D, mode, MN);
    if (mode) {
      const _Float16* pli = plT + (size_t)(i - 4) * D * D;
      // G4: partials = delta @ plastic (split-K x2)
      gemm6<5, 2><<<(M / 128) * (D / 128) * 2, 256, 0, stream>>>(
          d16, pli, M, D, D, pbig, nullptr, nullptr, nullptr, nullptr);
      xupd<<<(int)(MN / 256), 256, 0, stream>>>(pbig, x, x16, MN);
    }
  }

  final_norm<<<M, 256, 0, stream>>>(x, fnw, xf16, D);

  // LM head: logits = xf @ emb^T + fused row stats
  gemm6<0, 1><<<(M / 128) * (V / 128), 256, 0, stream>>>(
      xf16, emb16, M, V, D, out, nullptr, nullptr, psum, psq);

  // fused scale+clip (reduce partials per row, then stream the row)
  fix_row<<<M, 256, 0, stream>>>(out, psum, psq, PW, V);
}

// Round 7
// 1391.421 us; speedup vs baseline: 1.1208x; 1.0060x over previous
//
#include <hip/hip_runtime.h>

// ---------------------------------------------------------------------------
// MRT12 v7: head GEMM moves to a 256x256 / 8-wave / 4-quadrant-phase schedule
// (T2 swizzle + T3/T4 counted vmcnt + T5 setprio; 32 MFMA per barrier pair).
// Layer GEMMs keep the 128^2 depth-3 pipeline but gain the conflict-free
// XOR read swizzle (slot ^= (row>>1)&3, both-sides involution).
// B=2,S=1024,D=1024,L=8,V=32000. fp32 in/out.
// ---------------------------------------------------------------------------

using short8 = __attribute__((ext_vector_type(8))) short;
using half8  = __attribute__((ext_vector_type(8))) _Float16;
using f32x4  = __attribute__((ext_vector_type(4))) float;

#define DEVI __device__ __forceinline__

DEVI float sigm(float x) { return 1.0f / (1.0f + expf(-x)); }

DEVI float block_sum256(float v) {
  #pragma unroll
  for (int o = 32; o > 0; o >>= 1) v += __shfl_down(v, o, 64);
  __shared__ float sm[4];
  if ((threadIdx.x & 63) == 0) sm[threadIdx.x >> 6] = v;
  __syncthreads();
  float t = sm[0] + sm[1] + sm[2] + sm[3];
  __syncthreads();
  return t;
}

DEVI void gload16(const void* g, void* l) {    // async global->LDS, 16B/lane
  __builtin_amdgcn_global_load_lds(
      (const __attribute__((address_space(1))) unsigned*)g,
      (__attribute__((address_space(3))) unsigned*)l, 16, 0, 0);
}

// ---------------------------------------------------------------------------
// gemm8 (HEAD): C[M,N] = A[M,K] * B[N,K]^T, fp16 MFMA. 256x256 tile, BK=32,
// 8 waves (2x4), per-wave 128x64. 64KB LDS double-buffer. Per iter: counted
// vmcnt(4) + barrier, then 4 quadrant phases (no inner barriers, 8 MFMA each,
// setprio-wrapped), then barrier + re-stage K(T+2) into the just-read buffer.
// Conflict-free swizzle: 16B slot ^= (row>>1)&3 on source AND read.
// Fused per-row sum/sumsq partials for the logit std fix.
// ---------------------------------------------------------------------------
__global__ __launch_bounds__(512, 2) void gemm8(
    const _Float16* __restrict__ A, const _Float16* __restrict__ B,
    int M, int N, int K,
    float* __restrict__ outF, float* __restrict__ psum, float* __restrict__ psq)
{
  __shared__ __align__(16) unsigned short lds8[2][2][256 * 32];  // 64 KB
  const int tid  = threadIdx.x;                 // 0..511
  const int lane = tid & 63, wid = tid >> 6;    // 8 waves
  const int wr = wid >> 2, wc = wid & 3;        // 2 x 4 wave grid
  const int myr = lane & 15;
  const int kq  = lane >> 4;                    // 8-elem k-slot 0..3
  const int myq = lane >> 4;

  // XCD-chunked swizzle (nwg % 8 == 0), m-fastest decode
  const int nwg  = gridDim.x;
  const int flat = blockIdx.x;
  const int swz  = (flat & 7) * (nwg >> 3) + (flat >> 3);
  const int MT   = M >> 8;                      // 256-row tiles
  const int m0   = (swz % MT) * 256;
  const int nt   = swz / MT;
  const int n0   = nt * 256;
  const int NT   = K / 32;

  // staging: per K-tile per array 16 KB = 2 issues of 8 KB (512 thr x 16B).
  // wave covers 16 rows of 64B; LDS dest is the wave-uniform base (HW adds
  // lane*16). Source col pre-swizzled: slot ^= (row>>1)&3.
  const int strow = lane >> 2;                  // row within wave's 16
  const int stslot = lane & 3;                  // 16B slot in 64B row
  auto stage = [&](int b, int k0) {
    #pragma unroll
    for (int q = 0; q < 2; ++q) {
      const int row  = q * 128 + wid * 16 + strow;
      const int scol = (stslot ^ ((row >> 1) & 3)) << 3;   // elems
      const int lbase = (q * 128 + wid * 16) * 32;         // wave-uniform
      gload16(A + (size_t)(m0 + row) * K + k0 + scol, &lds8[b][0][lbase]);
      gload16(B + (size_t)(n0 + row) * K + k0 + scol, &lds8[b][1][lbase]);
    }
  };

  f32x4 acc[8][4] = {};

  stage(0, 0);
  stage(1, 32);
  for (int T = 0; T < NT; ++T) {
    if (T + 1 < NT) { asm volatile("s_waitcnt vmcnt(4)" ::: "memory"); }
    else            { asm volatile("s_waitcnt vmcnt(0)" ::: "memory"); }
    __builtin_amdgcn_s_barrier();               // K-tile T visible to all
    asm volatile("" ::: "memory");
    const int b = T & 1;

    #pragma unroll
    for (int q = 0; q < 4; ++q) {               // quadrant phases, no barriers
      const int qi = q >> 1, qj = q & 1;
      short8 af[4], bf2[2];
      #pragma unroll
      for (int i = 0; i < 4; ++i) {
        const int ra = wr * 128 + qi * 64 + i * 16 + myr;
        af[i] = *(const short8*)&lds8[b][0][ra * 32 + ((kq ^ ((ra >> 1) & 3)) << 3)];
      }
      #pragma unroll
      for (int j = 0; j < 2; ++j) {
        const int rb = wc * 64 + qj * 32 + j * 16 + myr;
        bf2[j] = *(const short8*)&lds8[b][1][rb * 32 + ((kq ^ ((rb >> 1) & 3)) << 3)];
      }
      __builtin_amdgcn_s_setprio(1);
      #pragma unroll
      for (int i = 0; i < 4; ++i)
        #pragma unroll
        for (int j = 0; j < 2; ++j)
          acc[qi * 4 + i][qj * 2 + j] = __builtin_amdgcn_mfma_f32_16x16x32_f16(
              __builtin_bit_cast(half8, af[i]), __builtin_bit_cast(half8, bf2[j]),
              acc[qi * 4 + i][qj * 2 + j], 0, 0, 0);
      __builtin_amdgcn_s_setprio(0);
    }

    if (T + 2 < NT) {                           // re-stage just-read buffer
      __builtin_amdgcn_s_barrier();             // all waves done reading buf b
      asm volatile("" ::: "memory");
      stage(b, (T + 2) * 32);
    }
  }

  // epilogue: C/D frag row=(lane>>4)*4+r, col=lane&15 (m89)
  #pragma unroll
  for (int i8 = 0; i8 < 8; ++i8) {
    const int rbase = m0 + wr * 128 + i8 * 16 + (myq << 2);
    #pragma unroll
    for (int j4 = 0; j4 < 4; ++j4) {
      const int col = n0 + wc * 64 + j4 * 16 + myr;
      #pragma unroll
      for (int r = 0; r < 4; ++r)
        outF[(size_t)(rbase + r) * N + col] = acc[i8][j4][r];
    }
  }

  // fused per-row stats over this wave's 64 output cols
  const int PW = N >> 6;
  const int pcol = (n0 >> 6) + wc;
  #pragma unroll
  for (int i8 = 0; i8 < 8; ++i8)
    #pragma unroll
    for (int r = 0; r < 4; ++r) {
      float s = 0.f, ss = 0.f;
      #pragma unroll
      for (int j4 = 0; j4 < 4; ++j4) {
        float v = acc[i8][j4][r];
        s += v; ss += v * v;
      }
      #pragma unroll
      for (int mk = 1; mk < 16; mk <<= 1) {
        s  += __shfl_xor(s,  mk, 64);
        ss += __shfl_xor(ss, mk, 64);
      }
      if (myr == ((i8 * 4 + r) & 15)) {
        const int row = m0 + wr * 128 + i8 * 16 + myq * 4 + r;
        psum[(size_t)row * PW + pcol] = s;
        psq [(size_t)row * PW + pcol] = ss;
      }
    }
}

// ---------------------------------------------------------------------------
// GEMM v6 (layers): 128x128, BK=32, depth-3 counted-vmcnt pipeline, now with
// conflict-free XOR swizzle (slot ^= (row>>1)&3) on source and read.
// EPI: 2 +bias,silu,fp16; 5 raw fp32 partial; 6 channel-major partial (G1)
// ---------------------------------------------------------------------------
template<int EPI, int KSPLIT>
__global__ __launch_bounds__(256, 3) void gemm6(
    const _Float16* __restrict__ A, const _Float16* __restrict__ B,
    int M, int N, int K,
    float* __restrict__ outF, _Float16* __restrict__ outH,
    const float* __restrict__ bias)
{
  __shared__ __align__(16) unsigned short lds[3][2][128 * 32];
  const int tid  = threadIdx.x;
  const int lane = tid & 63, wid = tid >> 6;
  const int wr = wid >> 1, wc = wid & 1;

  const int nwg  = gridDim.x;
  const int flat = blockIdx.x;
  const int swz  = (flat & 7) * (nwg >> 3) + (flat >> 3);
  const int ks   = (KSPLIT > 1) ? (swz % KSPLIT) : 0;
  const int tile = (KSPLIT > 1) ? (swz / KSPLIT) : swz;
  const int MT   = M >> 7;
  const int m0   = (tile % MT) * 128;
  const int n0   = (tile / MT) * 128;
  const int Kc   = K / KSPLIT;
  const int kbase = ks * Kc;
  const int NT   = Kc / 32;

  const int srow = lane >> 2;
  const int sslot = lane & 3;

  auto stage = [&](int b, int k0) {
    #pragma unroll
    for (int q = 0; q < 2; ++q) {
      const int row = wid * 32 + q * 16 + srow;
      const int scol = (sslot ^ ((row >> 1) & 3)) << 3;   // pre-swizzled src
      const int lo = wid * 1024 + q * 512;                // wave-uniform dest
      gload16(A + (size_t)(m0 + row) * K + k0 + scol, &lds[b][0][lo]);
      gload16(B + (size_t)(n0 + row) * K + k0 + scol, &lds[b][1][lo]);
    }
  };

  f32x4 acc[4][4] = {};
  const int myr = lane & 15;
  const int kq  = lane >> 4;

  stage(0, kbase);
  stage(1, kbase + 32);
  int cur = 0, nxt = 2;
  for (int t = 0; t < NT; ++t) {
    if (t + 1 < NT) { asm volatile("s_waitcnt vmcnt(4)" ::: "memory"); }
    else            { asm volatile("s_waitcnt vmcnt(0)" ::: "memory"); }
    __builtin_amdgcn_s_barrier();
    asm volatile("" ::: "memory");
    if (t + 2 < NT) stage(nxt, kbase + (t + 2) * 32);

    short8 af[4], bfr[4];
    #pragma unroll
    for (int i = 0; i < 4; ++i) {
      const int ra = wr * 64 + i * 16 + myr;
      af[i] = *(const short8*)&lds[cur][0][ra * 32 + ((kq ^ ((ra >> 1) & 3)) << 3)];
      const int rb = wc * 64 + i * 16 + myr;
      bfr[i] = *(const short8*)&lds[cur][1][rb * 32 + ((kq ^ ((rb >> 1) & 3)) << 3)];
    }
    #pragma unroll
    for (int i = 0; i < 4; ++i)
      #pragma unroll
      for (int j = 0; j < 4; ++j)
        acc[i][j] = __builtin_amdgcn_mfma_f32_16x16x32_f16(
            __builtin_bit_cast(half8, af[i]), __builtin_bit_cast(half8, bfr[j]),
            acc[i][j], 0, 0, 0);
    cur = (cur == 2) ? 0 : cur + 1;
    nxt = (nxt == 2) ? 0 : nxt + 1;
  }

  const size_t MN = (size_t)M * N;
  #pragma unroll
  for (int i = 0; i < 4; ++i) {
    const int rbase = m0 + wr * 64 + i * 16 + (kq << 2);
    #pragma unroll
    for (int j = 0; j < 4; ++j) {
      const int col = n0 + wc * 64 + j * 16 + myr;
      if constexpr (EPI == 6) {
        f32x4 v;
        #pragma unroll
        for (int r = 0; r < 4; ++r) v[r] = acc[i][j][r];
        *(f32x4*)&outF[(size_t)ks * MN + (size_t)col * M + rbase] = v;
      } else {
        #pragma unroll
        for (int r = 0; r < 4; ++r) {
          float c = acc[i][j][r];
          const size_t idx = (size_t)(rbase + r) * N + col;
          if constexpr (EPI == 2) {
            c += bias[col];
            outH[idx] = (_Float16)(c * sigm(c));
          } else if constexpr (EPI == 5) {
            outF[(size_t)ks * MN + idx] = c;
          }
        }
      }
    }
  }
}

// ---------------------------------------------------------------------------
// Fused split-K combine + tanh/sigm + lerp-scan + causal dwconv3.
// ---------------------------------------------------------------------------
__global__ __launch_bounds__(256) void scanconv2(
    const float* __restrict__ pbig, const float* __restrict__ cw,
    const float* __restrict__ cb, _Float16* __restrict__ z16,
    int S, int D, int M)
{
  const int dl = threadIdx.x & 7;
  const int c  = threadIdx.x >> 3;
  const int ch = blockIdx.x * 8 + dl;
  const int b = ch >> 10, d = ch & 1023;
  const size_t P1 = (size_t)2 * D * M;
  const float* t0 = pbig + (size_t)d * M + b * S;
  const float* a0 = pbig + (size_t)(D + d) * M + b * S;
  const int s0 = c * 32;

  f32x4 vr[8], ar[8];
  float A = 1.f, Bv = 0.f, Apm = 1.f, Bpm = 0.f;
  #pragma unroll
  for (int t = 0; t < 8; ++t) {
    f32x4 th  = *(const f32x4*)&t0[s0 + t * 4];
    f32x4 th2 = *(const f32x4*)&t0[P1 + s0 + t * 4];
    f32x4 aa  = *(const f32x4*)&a0[s0 + t * 4];
    f32x4 aa2 = *(const f32x4*)&a0[P1 + s0 + t * 4];
    #pragma unroll
    for (int r = 0; r < 4; ++r) {
      float v = tanhf(th[r] + th2[r]) * 3.14159265358979323846f;
      float a = sigm(aa[r] + aa2[r]);
      vr[t][r] = v; ar[t][r] = a;
      if (t * 4 + r == 31) { Apm = A; Bpm = Bv; }
      float na = 1.f - a;
      A *= na;
      Bv = Bv * na + a * v;
    }
  }
  __shared__ float Asm[32][9], Bsm[32][9], Aps[32][9], Bps[32][9];
  Asm[c][dl] = A; Bsm[c][dl] = Bv; Aps[c][dl] = Apm; Bps[c][dl] = Bpm;
  __syncthreads();
  if (threadIdx.x < 8) {
    float run = 0.f;
    for (int cc = 0; cc < 32; ++cc) {
      float A_ = Asm[cc][dl], B_ = Bsm[cc][dl];
      Bsm[cc][dl] = run;
      run = A_ * run + B_;
    }
  }
  __syncthreads();
  float hm1 = Bsm[c][dl];
  float hm2 = (c == 0) ? 0.f
            : (Aps[c - 1][dl] * Bsm[c - 1][dl] + Bps[c - 1][dl]);

  const float w0 = cw[d * 3 + 0], w1 = cw[d * 3 + 1], w2 = cw[d * 3 + 2];
  const float bc = cb[d];
  #pragma unroll
  for (int t = 0; t < 8; ++t) {
    #pragma unroll
    for (int r = 0; r < 4; ++r) {
      float h = hm1 + ar[t][r] * (vr[t][r] - hm1);
      float z = h + bc + w0 * hm2 + w1 * hm1 + w2 * h;
      z16[(size_t)(b * S + s0 + t * 4 + r) * D + d] = (_Float16)z;
      hm2 = hm1; hm1 = h;
    }
  }
}

__global__ __launch_bounds__(256) void rms_fuse(
    const float* __restrict__ p, const float* __restrict__ bias,
    const float* __restrict__ nw, float* __restrict__ x,
    _Float16* __restrict__ o16, int D, int mode, size_t MN)
{
  const size_t base = (size_t)blockIdx.x * D;
  float vloc[4]; float ss = 0.f;
  #pragma unroll
  for (int q = 0; q < 4; ++q) {
    int d = threadIdx.x + q * 256;
    float v = p[base + d] + p[MN + base + d] + bias[d];
    vloc[q] = v; ss += v * v;
  }
  ss = block_sum256(ss);
  float r = 1.f / sqrtf(ss / D + 1e-8f);
  #pragma unroll
  for (int q = 0; q < 4; ++q) {
    int d = threadIdx.x + q * 256;
    float delta = vloc[q] * r * nw[d];
    float xn = x[base + d] + delta;
    x[base + d] = xn;
    o16[base + d] = (_Float16)(mode ? delta : xn);
  }
}

__global__ __launch_bounds__(256) void xupd(
    const float* __restrict__ p, float* __restrict__ x,
    _Float16* __restrict__ x16, size_t MN)
{
  size_t i = (size_t)blockIdx.x * 256 + threadIdx.x;
  if (i >= MN) return;
  float xn = x[i] + p[i] + p[MN + i];
  x[i] = xn;
  x16[i] = (_Float16)xn;
}

__global__ __launch_bounds__(256) void embed_norm(
    const int* __restrict__ ids, const float* __restrict__ emb,
    const float* __restrict__ pos,
    float* __restrict__ x, _Float16* __restrict__ x16, int S, int D)
{
  const int rowi = blockIdx.x;
  const int s = rowi % S;
  const int tok = ids[rowi];
  const size_t eb = (size_t)tok * D, pb = (size_t)s * D, xb = (size_t)rowi * D;
  float vloc[4]; float ss = 0.f;
  #pragma unroll
  for (int q = 0; q < 4; ++q) {
    int d = threadIdx.x + q * 256;
    float v = emb[eb + d] + pos[pb + d];
    vloc[q] = v; ss += v * v;
  }
  ss = block_sum256(ss);
  float r = 1.f / fmaxf(sqrtf(ss), 1e-12f);
  #pragma unroll
  for (int q = 0; q < 4; ++q) {
    int d = threadIdx.x + q * 256;
    float v = vloc[q] * r;
    x[xb + d] = v;
    x16[xb + d] = (_Float16)v;
  }
}

__global__ __launch_bounds__(256) void final_norm(
    const float* __restrict__ x, const float* __restrict__ w,
    _Float16* __restrict__ xf, int D)
{
  const size_t base = (size_t)blockIdx.x * D;
  float s1 = 0.f, s2 = 0.f;
  float vloc[4], wloc[4];
  #pragma unroll
  for (int q = 0; q < 4; ++q) {
    int d = threadIdx.x + q * 256;
    float v = x[base + d], ww = w[d];
    vloc[q] = v; wloc[q] = ww;
    s1 += v * v; s2 += v * ww * v * ww;
  }
  s1 = block_sum256(s1);
  s2 = block_sum256(s2);
  float r1 = 1.f / sqrtf(s1 / D + 1e-8f);
  float m2 = r1 * r1 * (s2 / D);
  float r2 = 1.f / sqrtf(m2 + 1e-8f);
  float sc = r1 * r2 * 0.8f;
  #pragma unroll
  for (int q = 0; q < 4; ++q) {
    int d = threadIdx.x + q * 256;
    xf[base + d] = (_Float16)(vloc[q] * wloc[q] * sc);
  }
}

__global__ __launch_bounds__(256) void fix_row(
    float* __restrict__ out, const float* __restrict__ psum,
    const float* __restrict__ psq, int PW, int V)
{
  const int row = blockIdx.x;
  float s = 0.f, q = 0.f;
  for (int j = threadIdx.x; j < PW; j += 256) {
    s += psum[(size_t)row * PW + j];
    q += psq [(size_t)row * PW + j];
  }
  s = block_sum256(s);
  q = block_sum256(q);
  float mean = s / V;
  float var = (q - (float)V * mean * mean) / (float)(V - 1);
  var = fmaxf(var, 0.f);
  const float sc = 1.f / fmaxf(sqrtf(var), 1.f);
  float* rowp = out + (size_t)row * V;
  for (int j = threadIdx.x * 4; j < V; j += 1024) {
    f32x4 v = *(f32x4*)&rowp[j];
    #pragma unroll
    for (int t = 0; t < 4; ++t)
      v[t] = fminf(fmaxf(v[t] * sc, -10.f), 10.f);
    *(f32x4*)&rowp[j] = v;
  }
}

__global__ void tsplit16(const float* __restrict__ W, _Float16* __restrict__ WT,
                         int K, int N)
{
  __shared__ float t[32][33];
  const size_t bo = (size_t)blockIdx.z * K * N;
  const int tx = threadIdx.x, ty = threadIdx.y;
  #pragma unroll
  for (int i = 0; i < 32; i += 8) {
    int kk = blockIdx.y * 32 + ty + i;
    int nn = blockIdx.x * 32 + tx;
    t[ty + i][tx] = W[bo + (size_t)kk * N + nn];
  }
  __syncthreads();
  #pragma unroll
  for (int i = 0; i < 32; i += 8) {
    int nn = blockIdx.x * 32 + ty + i;
    int kk = blockIdx.y * 32 + tx;
    WT[bo + (size_t)nn * K + kk] = (_Float16)t[tx][ty + i];
  }
}

__global__ void cvt_f16(const float* __restrict__ in, _Float16* __restrict__ o, size_t n)
{
  for (size_t i = (size_t)blockIdx.x * 256 + threadIdx.x; i < n;
       i += (size_t)gridDim.x * 256)
    o[i] = (_Float16)in[i];
}

// ---------------------------------------------------------------------------
extern "C" void kernel_launch(void* const* d_in, const int* in_sizes, int n_in,
                              void* d_out, int out_size, void* d_ws, size_t ws_size,
                              hipStream_t stream)
{
  (void)in_sizes; (void)n_in; (void)out_size; (void)ws_size;
  const int*   ids = (const int*)  d_in[0];
  const float* emb = (const float*)d_in[1];
  const float* pos = (const float*)d_in[2];
  const float* kw  = (const float*)d_in[3];
  const float* cw  = (const float*)d_in[4];
  const float* cb  = (const float*)d_in[5];
  const float* w1  = (const float*)d_in[6];
  const float* b1  = (const float*)d_in[7];
  const float* w2  = (const float*)d_in[8];
  const float* b2  = (const float*)d_in[9];
  const float* nw  = (const float*)d_in[10];
  const float* pl  = (const float*)d_in[11];
  const float* fnw = (const float*)d_in[12];
  float* out = (float*)d_out;

  constexpr int B = 2, S = 1024, D = 1024, L = 8, V = 32000;
  constexpr int M = B * S;
  const size_t MN = (size_t)M * D;

  size_t off = 0;
  auto alloc = [&](size_t bytes) {
    char* p = (char*)d_ws + off;
    off += (bytes + 255) & ~(size_t)255;
    return (void*)p;
  };
  _Float16* kwT  = (_Float16*)alloc((size_t)L * 2 * D * D * 2);
  _Float16* w1T  = (_Float16*)alloc((size_t)L * 2 * D * D * 2);
  _Float16* w2T  = (_Float16*)alloc((size_t)L * 2 * D * D * 2);
  _Float16* plT  = (_Float16*)alloc((size_t)4 * D * D * 2);
  _Float16* emb16 = (_Float16*)alloc((size_t)V * D * 2);
  float* x    = (float*)alloc(MN * 4);
  _Float16* x16 = (_Float16*)alloc(MN * 2);
  float* pbig = (float*)alloc((size_t)2 * M * 2 * D * 4);
  _Float16* z16 = (_Float16*)alloc(MN * 2);
  _Float16* u16 = (_Float16*)alloc((size_t)M * 2 * D * 2);
  _Float16* d16 = (_Float16*)alloc(MN * 2);
  _Float16* xf16 = (_Float16*)alloc(MN * 2);

  const int PW = V >> 6;                 // 500
  float* psum = pbig;
  float* psq  = pbig + (size_t)M * PW;

  {
    dim3 tb(32, 8);
    tsplit16<<<dim3(2 * D / 32, D / 32, L), tb, 0, stream>>>(kw, kwT, D, 2 * D);
    tsplit16<<<dim3(2 * D / 32, D / 32, L), tb, 0, stream>>>(w1, w1T, D, 2 * D);
    tsplit16<<<dim3(D / 32, 2 * D / 32, L), tb, 0, stream>>>(w2, w2T, 2 * D, D);
    tsplit16<<<dim3(D / 32, D / 32, 4),     tb, 0, stream>>>(pl, plT, D, D);
    cvt_f16<<<4096, 256, 0, stream>>>(emb, emb16, (size_t)V * D);
  }

  embed_norm<<<M, 256, 0, stream>>>(ids, emb, pos, x, x16, S, D);

  for (int i = 0; i < L; ++i) {
    const _Float16* kwi = kwT + (size_t)i * 2 * D * D;
    const _Float16* w1i = w1T + (size_t)i * 2 * D * D;
    const _Float16* w2i = w2T + (size_t)i * 2 * D * D;

    // G1: partials = x@kw (split-K x2), channel-major [ks][2D][M]
    gemm6<6, 2><<<(M / 128) * (2 * D / 128) * 2, 256, 0, stream>>>(
        x16, kwi, M, 2 * D, D, pbig, nullptr, nullptr);

    scanconv2<<<B * D / 8, 256, 0, stream>>>(
        pbig, cw + (size_t)i * D * 3, cb + (size_t)i * D, z16, S, D, M);

    // G2: u = silu(z@w1 + b1) -> fp16
    gemm6<2, 1><<<(M / 128) * (2 * D / 128), 256, 0, stream>>>(
        z16, w1i, M, 2 * D, D, nullptr, u16, b1 + (size_t)i * 2 * D);

    // G3: hf partials = u@w2 (split-K x2)
    gemm6<5, 2><<<(M / 128) * (D / 128) * 2, 256, 0, stream>>>(
        u16, w2i, M, D, 2 * D, pbig, nullptr, nullptr);

    const int mode = (i >= L - 4) ? 1 : 0;
    rms_fuse<<<M, 256, 0, stream>>>(pbig, b2 + (size_t)i * D, nw + (size_t)i * D,
                                    x, mode ? d16 : x16, D, mode, MN);
    if (mode) {
      const _Float16* pli = plT + (size_t)(i - 4) * D * D;
      gemm6<5, 2><<<(M / 128) * (D / 128) * 2, 256, 0, stream>>>(
          d16, pli, M, D, D, pbig, nullptr, nullptr);
      xupd<<<(int)(MN / 256), 256, 0, stream>>>(pbig, x, x16, MN);
    }
  }

  final_norm<<<M, 256, 0, stream>>>(x, fnw, xf16, D);

  // LM head: 256^2 8-wave schedule + fused row stats
  gemm8<<<(M / 256) * (V / 256), 512, 0, stream>>>(
      xf16, emb16, M, V, D, out, psum, psq);

  fix_row<<<M, 256, 0, stream>>>(out, psum, psq, PW, V);
}

// Round 8
// 1311.563 us; speedup vs baseline: 1.1890x; 1.0609x over previous
//
#include <hip/hip_runtime.h>

// ---------------------------------------------------------------------------
// MRT12 v8: GEMMs rebuilt at BK=64 with register-held fragments (no LDS frag
// re-reads): head = 256^2/8-wave/128KB LDS, layers = 128^2/4-wave/64KB LDS.
// Per iter: [vmcnt(8); s_barrier] -> P0{12 reads, lgk0, 32 MFMA} ->
// P1{12 reads, lgk0, s_barrier, stage(t+2), 32 MFMA}. Swizzle slot^=(row&7)
// (HW-verified conflict-free, r4). B=2,S=1024,D=1024,L=8,V=32000. fp32 io.
// ---------------------------------------------------------------------------

using short8 = __attribute__((ext_vector_type(8))) short;
using half8  = __attribute__((ext_vector_type(8))) _Float16;
using f32x4  = __attribute__((ext_vector_type(4))) float;

#define DEVI __device__ __forceinline__

DEVI float sigm(float x) { return 1.0f / (1.0f + expf(-x)); }

DEVI float block_sum256(float v) {
  #pragma unroll
  for (int o = 32; o > 0; o >>= 1) v += __shfl_down(v, o, 64);
  __shared__ float sm[4];
  if ((threadIdx.x & 63) == 0) sm[threadIdx.x >> 6] = v;
  __syncthreads();
  float t = sm[0] + sm[1] + sm[2] + sm[3];
  __syncthreads();
  return t;
}

DEVI void gload16(const void* g, void* l) {    // async global->LDS, 16B/lane
  __builtin_amdgcn_global_load_lds(
      (const __attribute__((address_space(1))) unsigned*)g,
      (__attribute__((address_space(3))) unsigned*)l, 16, 0, 0);
}

// ---------------------------------------------------------------------------
// gemm9h (HEAD): C[M,N] = A[M,K]*B[N,K]^T fp16. 256x256, BK=64, 8 waves
// (2Mx4N, wave 128x64). LDS 128KB dbuf. Fused per-row sum/sumsq partials.
// ---------------------------------------------------------------------------
__global__ __launch_bounds__(512, 2) void gemm9h(
    const _Float16* __restrict__ A, const _Float16* __restrict__ B,
    int M, int N, int K,
    float* __restrict__ outF, float* __restrict__ psum, float* __restrict__ psq)
{
  __shared__ __align__(16) unsigned short lds[2][2][256 * 64];   // 128 KB
  const int tid  = threadIdx.x;
  const int lane = tid & 63, wid = tid >> 6;
  const int wr = wid >> 2, wc = wid & 3;        // 2 x 4 wave grid
  const int myr = lane & 15;
  const int kq  = lane >> 4;

  const int nwg  = gridDim.x;
  const int flat = blockIdx.x;
  const int swz  = (flat & 7) * (nwg >> 3) + (flat >> 3);
  const int MT   = M >> 8;
  const int m0   = (swz % MT) * 256;
  const int nt   = swz / MT;
  const int n0   = nt * 256;
  const int NT   = K / 64;

  auto stage = [&](int b, int k0) {
    #pragma unroll
    for (int q = 0; q < 4; ++q) {
      const int row  = q * 64 + wid * 8 + (lane >> 3);
      const int scol = ((lane & 7) ^ (row & 7)) << 3;
      const int lb   = (q * 64 + wid * 8) * 64;        // wave-uniform ushort
      gload16(A + (size_t)(m0 + row) * K + k0 + scol, &lds[b][0][lb]);
      gload16(B + (size_t)(n0 + row) * K + k0 + scol, &lds[b][1][lb]);
    }
  };

  f32x4 acc[8][4] = {};

  stage(0, 0);
  stage(1, 64);
  for (int t = 0; t < NT; ++t) {
    const int b = t & 1;
    if (t + 1 < NT) { asm volatile("s_waitcnt vmcnt(8)" ::: "memory"); }
    else            { asm volatile("s_waitcnt vmcnt(0)" ::: "memory"); }
    __builtin_amdgcn_s_barrier();               // tile t visible everywhere
    asm volatile("" ::: "memory");

    #pragma unroll
    for (int kk = 0; kk < 2; ++kk) {
      short8 af[8], bf[4];
      #pragma unroll
      for (int i = 0; i < 8; ++i) {
        const int ra = wr * 128 + i * 16 + myr;
        af[i] = *(const short8*)&lds[b][0][ra * 64 + (((kk * 4 + kq) ^ (ra & 7)) << 3)];
      }
      #pragma unroll
      for (int j = 0; j < 4; ++j) {
        const int rb = wc * 64 + j * 16 + myr;
        bf[j] = *(const short8*)&lds[b][1][rb * 64 + (((kk * 4 + kq) ^ (rb & 7)) << 3)];
      }
      asm volatile("s_waitcnt lgkmcnt(0)" ::: "memory");
      if (kk == 1) {                            // all reads of buf b done
        __builtin_amdgcn_s_barrier();
        asm volatile("" ::: "memory");
        if (t + 2 < NT) stage(b, (t + 2) * 64); // overlap stage with MFMAs
      }
      __builtin_amdgcn_sched_barrier(0);
      __builtin_amdgcn_s_setprio(1);
      #pragma unroll
      for (int i = 0; i < 8; ++i)
        #pragma unroll
        for (int j = 0; j < 4; ++j)
          acc[i][j] = __builtin_amdgcn_mfma_f32_16x16x32_f16(
              __builtin_bit_cast(half8, af[i]), __builtin_bit_cast(half8, bf[j]),
              acc[i][j], 0, 0, 0);
      __builtin_amdgcn_s_setprio(0);
    }
  }

  // epilogue (validated r7): C/D frag row=(lane>>4)*4+r, col=lane&15
  #pragma unroll
  for (int i8 = 0; i8 < 8; ++i8) {
    const int rbase = m0 + wr * 128 + i8 * 16 + (kq << 2);
    #pragma unroll
    for (int j4 = 0; j4 < 4; ++j4) {
      const int col = n0 + wc * 64 + j4 * 16 + myr;
      #pragma unroll
      for (int r = 0; r < 4; ++r)
        outF[(size_t)(rbase + r) * N + col] = acc[i8][j4][r];
    }
  }

  const int PW = N >> 6;
  const int pcol = (n0 >> 6) + wc;
  #pragma unroll
  for (int i8 = 0; i8 < 8; ++i8)
    #pragma unroll
    for (int r = 0; r < 4; ++r) {
      float s = 0.f, ss = 0.f;
      #pragma unroll
      for (int j4 = 0; j4 < 4; ++j4) {
        float v = acc[i8][j4][r];
        s += v; ss += v * v;
      }
      #pragma unroll
      for (int mk = 1; mk < 16; mk <<= 1) {
        s  += __shfl_xor(s,  mk, 64);
        ss += __shfl_xor(ss, mk, 64);
      }
      if (myr == ((i8 * 4 + r) & 15)) {
        const int row = m0 + wr * 128 + i8 * 16 + kq * 4 + r;
        psum[(size_t)row * PW + pcol] = s;
        psq [(size_t)row * PW + pcol] = ss;
      }
    }
}

// ---------------------------------------------------------------------------
// gemm9l (layers): 128x128, BK=64, 4 waves (2x2, wave 64x64), 64KB LDS dbuf.
// Same pipeline/swizzle as gemm9h. EPI: 2 +bias,silu,fp16; 5 raw fp32 partial
// (split-K); 6 channel-major partial (G1, split-K).
// ---------------------------------------------------------------------------
template<int EPI, int KSPLIT>
__global__ __launch_bounds__(256, 2) void gemm9l(
    const _Float16* __restrict__ A, const _Float16* __restrict__ B,
    int M, int N, int K,
    float* __restrict__ outF, _Float16* __restrict__ outH,
    const float* __restrict__ bias)
{
  __shared__ __align__(16) unsigned short lds[2][2][128 * 64];   // 64 KB
  const int tid  = threadIdx.x;
  const int lane = tid & 63, wid = tid >> 6;
  const int wr = wid >> 1, wc = wid & 1;
  const int myr = lane & 15;
  const int kq  = lane >> 4;

  const int nwg  = gridDim.x;
  const int flat = blockIdx.x;
  const int swz  = (flat & 7) * (nwg >> 3) + (flat >> 3);
  const int ks   = (KSPLIT > 1) ? (swz % KSPLIT) : 0;
  const int tile = (KSPLIT > 1) ? (swz / KSPLIT) : swz;
  const int MT   = M >> 7;
  const int m0   = (tile % MT) * 128;
  const int n0   = (tile / MT) * 128;
  const int Kc   = K / KSPLIT;
  const int kbase = ks * Kc;
  const int NT   = Kc / 64;

  auto stage = [&](int b, int k0) {
    #pragma unroll
    for (int q = 0; q < 4; ++q) {
      const int row  = q * 32 + wid * 8 + (lane >> 3);
      const int scol = ((lane & 7) ^ (row & 7)) << 3;
      const int lb   = (q * 32 + wid * 8) * 64;        // wave-uniform ushort
      gload16(A + (size_t)(m0 + row) * K + k0 + scol, &lds[b][0][lb]);
      gload16(B + (size_t)(n0 + row) * K + k0 + scol, &lds[b][1][lb]);
    }
  };

  f32x4 acc[4][4] = {};

  stage(0, kbase);
  stage(1, kbase + 64);
  for (int t = 0; t < NT; ++t) {
    const int b = t & 1;
    if (t + 1 < NT) { asm volatile("s_waitcnt vmcnt(8)" ::: "memory"); }
    else            { asm volatile("s_waitcnt vmcnt(0)" ::: "memory"); }
    __builtin_amdgcn_s_barrier();
    asm volatile("" ::: "memory");

    #pragma unroll
    for (int kk = 0; kk < 2; ++kk) {
      short8 af[4], bf[4];
      #pragma unroll
      for (int i = 0; i < 4; ++i) {
        const int ra = wr * 64 + i * 16 + myr;
        af[i] = *(const short8*)&lds[b][0][ra * 64 + (((kk * 4 + kq) ^ (ra & 7)) << 3)];
      }
      #pragma unroll
      for (int j = 0; j < 4; ++j) {
        const int rb = wc * 64 + j * 16 + myr;
        bf[j] = *(const short8*)&lds[b][1][rb * 64 + (((kk * 4 + kq) ^ (rb & 7)) << 3)];
      }
      asm volatile("s_waitcnt lgkmcnt(0)" ::: "memory");
      if (kk == 1) {
        __builtin_amdgcn_s_barrier();
        asm volatile("" ::: "memory");
        if (t + 2 < NT) stage(b, kbase + (t + 2) * 64);
      }
      __builtin_amdgcn_sched_barrier(0);
      __builtin_amdgcn_s_setprio(1);
      #pragma unroll
      for (int i = 0; i < 4; ++i)
        #pragma unroll
        for (int j = 0; j < 4; ++j)
          acc[i][j] = __builtin_amdgcn_mfma_f32_16x16x32_f16(
              __builtin_bit_cast(half8, af[i]), __builtin_bit_cast(half8, bf[j]),
              acc[i][j], 0, 0, 0);
      __builtin_amdgcn_s_setprio(0);
    }
  }

  const size_t MN = (size_t)M * N;
  #pragma unroll
  for (int i = 0; i < 4; ++i) {
    const int rbase = m0 + wr * 64 + i * 16 + (kq << 2);
    #pragma unroll
    for (int j = 0; j < 4; ++j) {
      const int col = n0 + wc * 64 + j * 16 + myr;
      if constexpr (EPI == 6) {
        f32x4 v;
        #pragma unroll
        for (int r = 0; r < 4; ++r) v[r] = acc[i][j][r];
        *(f32x4*)&outF[(size_t)ks * MN + (size_t)col * M + rbase] = v;
      } else {
        #pragma unroll
        for (int r = 0; r < 4; ++r) {
          float c = acc[i][j][r];
          const size_t idx = (size_t)(rbase + r) * N + col;
          if constexpr (EPI == 2) {
            c += bias[col];
            outH[idx] = (_Float16)(c * sigm(c));
          } else if constexpr (EPI == 5) {
            outF[(size_t)ks * MN + idx] = c;
          }
        }
      }
    }
  }
}

// ---------------------------------------------------------------------------
// Fused split-K combine + tanh/sigm + lerp-scan + causal dwconv3.
// ---------------------------------------------------------------------------
__global__ __launch_bounds__(256) void scanconv2(
    const float* __restrict__ pbig, const float* __restrict__ cw,
    const float* __restrict__ cb, _Float16* __restrict__ z16,
    int S, int D, int M)
{
  const int dl = threadIdx.x & 7;
  const int c  = threadIdx.x >> 3;
  const int ch = blockIdx.x * 8 + dl;
  const int b = ch >> 10, d = ch & 1023;
  const size_t P1 = (size_t)2 * D * M;
  const float* t0 = pbig + (size_t)d * M + b * S;
  const float* a0 = pbig + (size_t)(D + d) * M + b * S;
  const int s0 = c * 32;

  f32x4 vr[8], ar[8];
  float A = 1.f, Bv = 0.f, Apm = 1.f, Bpm = 0.f;
  #pragma unroll
  for (int t = 0; t < 8; ++t) {
    f32x4 th  = *(const f32x4*)&t0[s0 + t * 4];
    f32x4 th2 = *(const f32x4*)&t0[P1 + s0 + t * 4];
    f32x4 aa  = *(const f32x4*)&a0[s0 + t * 4];
    f32x4 aa2 = *(const f32x4*)&a0[P1 + s0 + t * 4];
    #pragma unroll
    for (int r = 0; r < 4; ++r) {
      float v = tanhf(th[r] + th2[r]) * 3.14159265358979323846f;
      float a = sigm(aa[r] + aa2[r]);
      vr[t][r] = v; ar[t][r] = a;
      if (t * 4 + r == 31) { Apm = A; Bpm = Bv; }
      float na = 1.f - a;
      A *= na;
      Bv = Bv * na + a * v;
    }
  }
  __shared__ float Asm[32][9], Bsm[32][9], Aps[32][9], Bps[32][9];
  Asm[c][dl] = A; Bsm[c][dl] = Bv; Aps[c][dl] = Apm; Bps[c][dl] = Bpm;
  __syncthreads();
  if (threadIdx.x < 8) {
    float run = 0.f;
    for (int cc = 0; cc < 32; ++cc) {
      float A_ = Asm[cc][dl], B_ = Bsm[cc][dl];
      Bsm[cc][dl] = run;
      run = A_ * run + B_;
    }
  }
  __syncthreads();
  float hm1 = Bsm[c][dl];
  float hm2 = (c == 0) ? 0.f
            : (Aps[c - 1][dl] * Bsm[c - 1][dl] + Bps[c - 1][dl]);

  const float w0 = cw[d * 3 + 0], w1 = cw[d * 3 + 1], w2 = cw[d * 3 + 2];
  const float bc = cb[d];
  #pragma unroll
  for (int t = 0; t < 8; ++t) {
    #pragma unroll
    for (int r = 0; r < 4; ++r) {
      float h = hm1 + ar[t][r] * (vr[t][r] - hm1);
      float z = h + bc + w0 * hm2 + w1 * hm1 + w2 * h;
      z16[(size_t)(b * S + s0 + t * 4 + r) * D + d] = (_Float16)z;
      hm2 = hm1; hm1 = h;
    }
  }
}

__global__ __launch_bounds__(256) void rms_fuse(
    const float* __restrict__ p, const float* __restrict__ bias,
    const float* __restrict__ nw, float* __restrict__ x,
    _Float16* __restrict__ o16, int D, int mode, size_t MN)
{
  const size_t base = (size_t)blockIdx.x * D;
  float vloc[4]; float ss = 0.f;
  #pragma unroll
  for (int q = 0; q < 4; ++q) {
    int d = threadIdx.x + q * 256;
    float v = p[base + d] + p[MN + base + d] + bias[d];
    vloc[q] = v; ss += v * v;
  }
  ss = block_sum256(ss);
  float r = 1.f / sqrtf(ss / D + 1e-8f);
  #pragma unroll
  for (int q = 0; q < 4; ++q) {
    int d = threadIdx.x + q * 256;
    float delta = vloc[q] * r * nw[d];
    float xn = x[base + d] + delta;
    x[base + d] = xn;
    o16[base + d] = (_Float16)(mode ? delta : xn);
  }
}

__global__ __launch_bounds__(256) void xupd(
    const float* __restrict__ p, float* __restrict__ x,
    _Float16* __restrict__ x16, size_t MN)
{
  size_t i = (size_t)blockIdx.x * 256 + threadIdx.x;
  if (i >= MN) return;
  float xn = x[i] + p[i] + p[MN + i];
  x[i] = xn;
  x16[i] = (_Float16)xn;
}

__global__ __launch_bounds__(256) void embed_norm(
    const int* __restrict__ ids, const float* __restrict__ emb,
    const float* __restrict__ pos,
    float* __restrict__ x, _Float16* __restrict__ x16, int S, int D)
{
  const int rowi = blockIdx.x;
  const int s = rowi % S;
  const int tok = ids[rowi];
  const size_t eb = (size_t)tok * D, pb = (size_t)s * D, xb = (size_t)rowi * D;
  float vloc[4]; float ss = 0.f;
  #pragma unroll
  for (int q = 0; q < 4; ++q) {
    int d = threadIdx.x + q * 256;
    float v = emb[eb + d] + pos[pb + d];
    vloc[q] = v; ss += v * v;
  }
  ss = block_sum256(ss);
  float r = 1.f / fmaxf(sqrtf(ss), 1e-12f);
  #pragma unroll
  for (int q = 0; q < 4; ++q) {
    int d = threadIdx.x + q * 256;
    float v = vloc[q] * r;
    x[xb + d] = v;
    x16[xb + d] = (_Float16)v;
  }
}

__global__ __launch_bounds__(256) void final_norm(
    const float* __restrict__ x, const float* __restrict__ w,
    _Float16* __restrict__ xf, int D)
{
  const size_t base = (size_t)blockIdx.x * D;
  float s1 = 0.f, s2 = 0.f;
  float vloc[4], wloc[4];
  #pragma unroll
  for (int q = 0; q < 4; ++q) {
    int d = threadIdx.x + q * 256;
    float v = x[base + d], ww = w[d];
    vloc[q] = v; wloc[q] = ww;
    s1 += v * v; s2 += v * ww * v * ww;
  }
  s1 = block_sum256(s1);
  s2 = block_sum256(s2);
  float r1 = 1.f / sqrtf(s1 / D + 1e-8f);
  float m2 = r1 * r1 * (s2 / D);
  float r2 = 1.f / sqrtf(m2 + 1e-8f);
  float sc = r1 * r2 * 0.8f;
  #pragma unroll
  for (int q = 0; q < 4; ++q) {
    int d = threadIdx.x + q * 256;
    xf[base + d] = (_Float16)(vloc[q] * wloc[q] * sc);
  }
}

__global__ __launch_bounds__(256) void fix_row(
    float* __restrict__ out, const float* __restrict__ psum,
    const float* __restrict__ psq, int PW, int V)
{
  const int row = blockIdx.x;
  float s = 0.f, q = 0.f;
  for (int j = threadIdx.x; j < PW; j += 256) {
    s += psum[(size_t)row * PW + j];
    q += psq [(size_t)row * PW + j];
  }
  s = block_sum256(s);
  q = block_sum256(q);
  float mean = s / V;
  float var = (q - (float)V * mean * mean) / (float)(V - 1);
  var = fmaxf(var, 0.f);
  const float sc = 1.f / fmaxf(sqrtf(var), 1.f);
  float* rowp = out + (size_t)row * V;
  for (int j = threadIdx.x * 4; j < V; j += 1024) {
    f32x4 v = *(f32x4*)&rowp[j];
    #pragma unroll
    for (int t = 0; t < 4; ++t)
      v[t] = fminf(fmaxf(v[t] * sc, -10.f), 10.f);
    *(f32x4*)&rowp[j] = v;
  }
}

__global__ void tsplit16(const float* __restrict__ W, _Float16* __restrict__ WT,
                         int K, int N)
{
  __shared__ float t[32][33];
  const size_t bo = (size_t)blockIdx.z * K * N;
  const int tx = threadIdx.x, ty = threadIdx.y;
  #pragma unroll
  for (int i = 0; i < 32; i += 8) {
    int kk = blockIdx.y * 32 + ty + i;
    int nn = blockIdx.x * 32 + tx;
    t[ty + i][tx] = W[bo + (size_t)kk * N + nn];
  }
  __syncthreads();
  #pragma unroll
  for (int i = 0; i < 32; i += 8) {
    int nn = blockIdx.x * 32 + ty + i;
    int kk = blockIdx.y * 32 + tx;
    WT[bo + (size_t)nn * K + kk] = (_Float16)t[tx][ty + i];
  }
}

__global__ void cvt_f16(const float* __restrict__ in, _Float16* __restrict__ o, size_t n)
{
  for (size_t i = (size_t)blockIdx.x * 256 + threadIdx.x; i < n;
       i += (size_t)gridDim.x * 256)
    o[i] = (_Float16)in[i];
}

// ---------------------------------------------------------------------------
extern "C" void kernel_launch(void* const* d_in, const int* in_sizes, int n_in,
                              void* d_out, int out_size, void* d_ws, size_t ws_size,
                              hipStream_t stream)
{
  (void)in_sizes; (void)n_in; (void)out_size; (void)ws_size;
  const int*   ids = (const int*)  d_in[0];
  const float* emb = (const float*)d_in[1];
  const float* pos = (const float*)d_in[2];
  const float* kw  = (const float*)d_in[3];
  const float* cw  = (const float*)d_in[4];
  const float* cb  = (const float*)d_in[5];
  const float* w1  = (const float*)d_in[6];
  const float* b1  = (const float*)d_in[7];
  const float* w2  = (const float*)d_in[8];
  const float* b2  = (const float*)d_in[9];
  const float* nw  = (const float*)d_in[10];
  const float* pl  = (const float*)d_in[11];
  const float* fnw = (const float*)d_in[12];
  float* out = (float*)d_out;

  constexpr int B = 2, S = 1024, D = 1024, L = 8, V = 32000;
  constexpr int M = B * S;
  const size_t MN = (size_t)M * D;

  size_t off = 0;
  auto alloc = [&](size_t bytes) {
    char* p = (char*)d_ws + off;
    off += (bytes + 255) & ~(size_t)255;
    return (void*)p;
  };
  _Float16* kwT  = (_Float16*)alloc((size_t)L * 2 * D * D * 2);
  _Float16* w1T  = (_Float16*)alloc((size_t)L * 2 * D * D * 2);
  _Float16* w2T  = (_Float16*)alloc((size_t)L * 2 * D * D * 2);
  _Float16* plT  = (_Float16*)alloc((size_t)4 * D * D * 2);
  _Float16* emb16 = (_Float16*)alloc((size_t)V * D * 2);
  float* x    = (float*)alloc(MN * 4);
  _Float16* x16 = (_Float16*)alloc(MN * 2);
  float* pbig = (float*)alloc((size_t)2 * M * 2 * D * 4);
  _Float16* z16 = (_Float16*)alloc(MN * 2);
  _Float16* u16 = (_Float16*)alloc((size_t)M * 2 * D * 2);
  _Float16* d16 = (_Float16*)alloc(MN * 2);
  _Float16* xf16 = (_Float16*)alloc(MN * 2);

  const int PW = V >> 6;                 // 500
  float* psum = pbig;
  float* psq  = pbig + (size_t)M * PW;

  {
    dim3 tb(32, 8);
    tsplit16<<<dim3(2 * D / 32, D / 32, L), tb, 0, stream>>>(kw, kwT, D, 2 * D);
    tsplit16<<<dim3(2 * D / 32, D / 32, L), tb, 0, stream>>>(w1, w1T, D, 2 * D);
    tsplit16<<<dim3(D / 32, 2 * D / 32, L), tb, 0, stream>>>(w2, w2T, 2 * D, D);
    tsplit16<<<dim3(D / 32, D / 32, 4),     tb, 0, stream>>>(pl, plT, D, D);
    cvt_f16<<<4096, 256, 0, stream>>>(emb, emb16, (size_t)V * D);
  }

  embed_norm<<<M, 256, 0, stream>>>(ids, emb, pos, x, x16, S, D);

  for (int i = 0; i < L; ++i) {
    const _Float16* kwi = kwT + (size_t)i * 2 * D * D;
    const _Float16* w1i = w1T + (size_t)i * 2 * D * D;
    const _Float16* w2i = w2T + (size_t)i * 2 * D * D;

    // G1: partials = x@kw (split-K x2, Kc=512, NT=8), channel-major
    gemm9l<6, 2><<<(M / 128) * (2 * D / 128) * 2, 256, 0, stream>>>(
        x16, kwi, M, 2 * D, D, pbig, nullptr, nullptr);

    scanconv2<<<B * D / 8, 256, 0, stream>>>(
        pbig, cw + (size_t)i * D * 3, cb + (size_t)i * D, z16, S, D, M);

    // G2: u = silu(z@w1 + b1) -> fp16 (NT=16)
    gemm9l<2, 1><<<(M / 128) * (2 * D / 128), 256, 0, stream>>>(
        z16, w1i, M, 2 * D, D, nullptr, u16, b1 + (size_t)i * 2 * D);

    // G3: hf partials = u@w2 (split-K x2, Kc=1024, NT=16)
    gemm9l<5, 2><<<(M / 128) * (D / 128) * 2, 256, 0, stream>>>(
        u16, w2i, M, D, 2 * D, pbig, nullptr, nullptr);

    const int mode = (i >= L - 4) ? 1 : 0;
    rms_fuse<<<M, 256, 0, stream>>>(pbig, b2 + (size_t)i * D, nw + (size_t)i * D,
                                    x, mode ? d16 : x16, D, mode, MN);
    if (mode) {
      const _Float16* pli = plT + (size_t)(i - 4) * D * D;
      // G4: partials = delta @ plastic (split-K x2, Kc=512, NT=8)
      gemm9l<5, 2><<<(M / 128) * (D / 128) * 2, 256, 0, stream>>>(
          d16, pli, M, D, D, pbig, nullptr, nullptr);
      xupd<<<(int)(MN / 256), 256, 0, stream>>>(pbig, x, x16, MN);
    }
  }

  final_norm<<<M, 256, 0, stream>>>(x, fnw, xf16, D);

  // LM head: 256^2 BK=64 held-frag schedule + fused row stats (NT=16)
  gemm9h<<<(M / 256) * (V / 256), 512, 0, stream>>>(
      xf16, emb16, M, V, D, out, psum, psq);

  fix_row<<<M, 256, 0, stream>>>(out, psum, psq, PW, V);
}

// Round 9
// 1171.725 us; speedup vs baseline: 1.3309x; 1.1193x over previous
//
#include <hip/hip_runtime.h>

// ---------------------------------------------------------------------------
// MRT12 v9: single GEMM template (128x128, BK=64, 4 waves, 64KB LDS dbuf,
// counted vmcnt(8), held fragments, conflict-free slot^=(row&7) swizzle,
// 2 blocks/CU). Head uses it too (cross-block overlap > 256^2 lockstep).
// Split-K dropped where the fp32-partial detour costs more than it saves:
// G1 -> fused tanh/sigm epilogue writes vaT directly; G4 -> direct x+=C.
// B=2,S=1024,D=1024,L=8,V=32000. fp32 in/out.
// ---------------------------------------------------------------------------

using short8 = __attribute__((ext_vector_type(8))) short;
using half8  = __attribute__((ext_vector_type(8))) _Float16;
using f32x4  = __attribute__((ext_vector_type(4))) float;

#define DEVI __device__ __forceinline__

DEVI float sigm(float x) { return 1.0f / (1.0f + expf(-x)); }

DEVI float block_sum256(float v) {
  #pragma unroll
  for (int o = 32; o > 0; o >>= 1) v += __shfl_down(v, o, 64);
  __shared__ float sm[4];
  if ((threadIdx.x & 63) == 0) sm[threadIdx.x >> 6] = v;
  __syncthreads();
  float t = sm[0] + sm[1] + sm[2] + sm[3];
  __syncthreads();
  return t;
}

DEVI void gload16(const void* g, void* l) {    // async global->LDS, 16B/lane
  __builtin_amdgcn_global_load_lds(
      (const __attribute__((address_space(1))) unsigned*)g,
      (__attribute__((address_space(3))) unsigned*)l, 16, 0, 0);
}

// ---------------------------------------------------------------------------
// gemm9: C[M,N] = A[M,K]*B[N,K]^T fp16 MFMA. 128x128, BK=64, 4 waves (2x2,
// wave 64x64), 64KB LDS dbuf, counted vmcnt(8), reg-held fragments.
// EPI: 0 head (fp32 C + fused row sum/sumsq partials)
//      1 keygen -> vaT[2D][M] channel-major, tanh*pi | sigmoid (fused act)
//      2 +bias, silu, fp16 out [M][N]
//      4 x += C in place (fp32), write x16
//      5 raw fp32 partial at outF + ks*M*N (split-K)
// ---------------------------------------------------------------------------
template<int EPI, int KSPLIT>
__global__ __launch_bounds__(256, 2) void gemm9(
    const _Float16* __restrict__ A, const _Float16* __restrict__ B,
    int M, int N, int K,
    float* __restrict__ outF, _Float16* __restrict__ outH,
    const float* __restrict__ bias,
    float* __restrict__ psum, float* __restrict__ psq, int halfN)
{
  __shared__ __align__(16) unsigned short lds[2][2][128 * 64];   // 64 KB
  const int tid  = threadIdx.x;
  const int lane = tid & 63, wid = tid >> 6;
  const int wr = wid >> 1, wc = wid & 1;
  const int myr = lane & 15;
  const int kq  = lane >> 4;

  const int nwg  = gridDim.x;
  const int flat = blockIdx.x;
  const int swz  = (flat & 7) * (nwg >> 3) + (flat >> 3);
  const int ks   = (KSPLIT > 1) ? (swz % KSPLIT) : 0;
  const int tile = (KSPLIT > 1) ? (swz / KSPLIT) : swz;
  const int MT   = M >> 7;
  const int m0   = (tile % MT) * 128;
  const int nt   = tile / MT;
  const int n0   = nt * 128;
  const int Kc   = K / KSPLIT;
  const int kbase = ks * Kc;
  const int NT   = Kc / 64;

  auto stage = [&](int b, int k0) {
    #pragma unroll
    for (int q = 0; q < 4; ++q) {
      const int row  = q * 32 + wid * 8 + (lane >> 3);
      const int scol = ((lane & 7) ^ (row & 7)) << 3;
      const int lb   = (q * 32 + wid * 8) * 64;        // wave-uniform ushort
      gload16(A + (size_t)(m0 + row) * K + k0 + scol, &lds[b][0][lb]);
      gload16(B + (size_t)(n0 + row) * K + k0 + scol, &lds[b][1][lb]);
    }
  };

  f32x4 acc[4][4] = {};

  stage(0, kbase);
  stage(1, kbase + 64);
  for (int t = 0; t < NT; ++t) {
    const int b = t & 1;
    if (t + 1 < NT) { asm volatile("s_waitcnt vmcnt(8)" ::: "memory"); }
    else            { asm volatile("s_waitcnt vmcnt(0)" ::: "memory"); }
    __builtin_amdgcn_s_barrier();
    asm volatile("" ::: "memory");

    #pragma unroll
    for (int kk = 0; kk < 2; ++kk) {
      short8 af[4], bf[4];
      #pragma unroll
      for (int i = 0; i < 4; ++i) {
        const int ra = wr * 64 + i * 16 + myr;
        af[i] = *(const short8*)&lds[b][0][ra * 64 + (((kk * 4 + kq) ^ (ra & 7)) << 3)];
      }
      #pragma unroll
      for (int j = 0; j < 4; ++j) {
        const int rb = wc * 64 + j * 16 + myr;
        bf[j] = *(const short8*)&lds[b][1][rb * 64 + (((kk * 4 + kq) ^ (rb & 7)) << 3)];
      }
      asm volatile("s_waitcnt lgkmcnt(0)" ::: "memory");
      if (kk == 1) {
        __builtin_amdgcn_s_barrier();
        asm volatile("" ::: "memory");
        if (t + 2 < NT) stage(b, kbase + (t + 2) * 64);
      }
      __builtin_amdgcn_sched_barrier(0);
      __builtin_amdgcn_s_setprio(1);
      #pragma unroll
      for (int i = 0; i < 4; ++i)
        #pragma unroll
        for (int j = 0; j < 4; ++j)
          acc[i][j] = __builtin_amdgcn_mfma_f32_16x16x32_f16(
              __builtin_bit_cast(half8, af[i]), __builtin_bit_cast(half8, bf[j]),
              acc[i][j], 0, 0, 0);
      __builtin_amdgcn_s_setprio(0);
    }
  }

  // epilogue: C/D frag row=(lane>>4)*4+r, col=lane&15 (m89)
  const size_t MN = (size_t)M * N;
  #pragma unroll
  for (int i = 0; i < 4; ++i) {
    const int rbase = m0 + wr * 64 + i * 16 + (kq << 2);
    #pragma unroll
    for (int j = 0; j < 4; ++j) {
      const int col = n0 + wc * 64 + j * 16 + myr;
      if constexpr (EPI == 1) {                    // channel-major vaT[col][row]
        f32x4 v;
        #pragma unroll
        for (int r = 0; r < 4; ++r) {
          float c = acc[i][j][r];
          v[r] = (col < halfN) ? (tanhf(c) * 3.14159265358979323846f) : sigm(c);
        }
        *(f32x4*)&outF[(size_t)col * M + rbase] = v;
      } else {
        #pragma unroll
        for (int r = 0; r < 4; ++r) {
          float c = acc[i][j][r];
          const size_t idx = (size_t)(rbase + r) * N + col;
          if constexpr (EPI == 0) {
            outF[idx] = c;
          } else if constexpr (EPI == 2) {
            c += bias[col];
            outH[idx] = (_Float16)(c * sigm(c));   // silu
          } else if constexpr (EPI == 4) {
            float xn = outF[idx] + c;              // x += delta@plastic
            outF[idx] = xn;
            outH[idx] = (_Float16)xn;
          } else if constexpr (EPI == 5) {
            outF[(size_t)ks * MN + idx] = c;
          }
        }
      }
    }
  }

  if constexpr (EPI == 0) {                        // fused row stats (head)
    const int PW = N >> 6;
    const int pcol = nt * 2 + wc;
    #pragma unroll
    for (int i = 0; i < 4; ++i)
      #pragma unroll
      for (int r = 0; r < 4; ++r) {
        float s = 0.f, ss = 0.f;
        #pragma unroll
        for (int j = 0; j < 4; ++j) {
          float v = acc[i][j][r];
          s += v; ss += v * v;
        }
        #pragma unroll
        for (int mk = 1; mk < 16; mk <<= 1) {
          s  += __shfl_xor(s,  mk, 64);
          ss += __shfl_xor(ss, mk, 64);
        }
        if (myr == i * 4 + r) {
          const int row = m0 + wr * 64 + i * 16 + kq * 4 + r;
          psum[(size_t)row * PW + pcol] = s;
          psq [(size_t)row * PW + pcol] = ss;
        }
      }
  }
}

// ---------------------------------------------------------------------------
// Fused lerp-scan + causal dwconv3. vaT[2D][M] channel-major, activations
// already applied by G1's epilogue. 8 channels x 32 chunks of 32 steps.
// ---------------------------------------------------------------------------
__global__ __launch_bounds__(256) void scanconv(
    const float* __restrict__ vaT, const float* __restrict__ cw,
    const float* __restrict__ cb, _Float16* __restrict__ z16,
    int S, int D, int M)
{
  const int dl = threadIdx.x & 7;
  const int c  = threadIdx.x >> 3;
  const int ch = blockIdx.x * 8 + dl;
  const int b = ch >> 10, d = ch & 1023;
  const float* vrow = vaT + (size_t)d * M + b * S;
  const float* arow = vaT + (size_t)(D + d) * M + b * S;
  const int s0 = c * 32;

  f32x4 vr[8], ar[8];
  float A = 1.f, Bv = 0.f, Apm = 1.f, Bpm = 0.f;
  #pragma unroll
  for (int t = 0; t < 8; ++t) {
    vr[t] = *(const f32x4*)&vrow[s0 + t * 4];
    ar[t] = *(const f32x4*)&arow[s0 + t * 4];
    #pragma unroll
    for (int r = 0; r < 4; ++r) {
      if (t * 4 + r == 31) { Apm = A; Bpm = Bv; }
      float na = 1.f - ar[t][r];
      A *= na;
      Bv = Bv * na + ar[t][r] * vr[t][r];
    }
  }
  __shared__ float Asm[32][9], Bsm[32][9], Aps[32][9], Bps[32][9];
  Asm[c][dl] = A; Bsm[c][dl] = Bv; Aps[c][dl] = Apm; Bps[c][dl] = Bpm;
  __syncthreads();
  if (threadIdx.x < 8) {                         // serial exclusive prefix
    float run = 0.f;
    for (int cc = 0; cc < 32; ++cc) {
      float A_ = Asm[cc][dl], B_ = Bsm[cc][dl];
      Bsm[cc][dl] = run;
      run = A_ * run + B_;
    }
  }
  __syncthreads();
  float hm1 = Bsm[c][dl];
  float hm2 = (c == 0) ? 0.f
            : (Aps[c - 1][dl] * Bsm[c - 1][dl] + Bps[c - 1][dl]);

  const float w0 = cw[d * 3 + 0], w1 = cw[d * 3 + 1], w2 = cw[d * 3 + 2];
  const float bc = cb[d];
  #pragma unroll
  for (int t = 0; t < 8; ++t) {
    #pragma unroll
    for (int r = 0; r < 4; ++r) {
      float h = hm1 + ar[t][r] * (vr[t][r] - hm1);
      float z = h + bc + w0 * hm2 + w1 * hm1 + w2 * h;
      z16[(size_t)(b * S + s0 + t * 4 + r) * D + d] = (_Float16)z;
      hm2 = hm1; hm1 = h;
    }
  }
}

// v = p0+p1+bias; delta = rmsnorm(v)*nw; x += delta; o16 = fp16(mode?delta:x)
__global__ __launch_bounds__(256) void rms_fuse(
    const float* __restrict__ p, const float* __restrict__ bias,
    const float* __restrict__ nw, float* __restrict__ x,
    _Float16* __restrict__ o16, int D, int mode, size_t MN)
{
  const size_t base = (size_t)blockIdx.x * D;
  float vloc[4]; float ss = 0.f;
  #pragma unroll
  for (int q = 0; q < 4; ++q) {
    int d = threadIdx.x + q * 256;
    float v = p[base + d] + p[MN + base + d] + bias[d];
    vloc[q] = v; ss += v * v;
  }
  ss = block_sum256(ss);
  float r = 1.f / sqrtf(ss / D + 1e-8f);
  #pragma unroll
  for (int q = 0; q < 4; ++q) {
    int d = threadIdx.x + q * 256;
    float delta = vloc[q] * r * nw[d];
    float xn = x[base + d] + delta;
    x[base + d] = xn;
    o16[base + d] = (_Float16)(mode ? delta : xn);
  }
}

__global__ __launch_bounds__(256) void embed_norm(
    const int* __restrict__ ids, const float* __restrict__ emb,
    const float* __restrict__ pos,
    float* __restrict__ x, _Float16* __restrict__ x16, int S, int D)
{
  const int rowi = blockIdx.x;
  const int s = rowi % S;
  const int tok = ids[rowi];
  const size_t eb = (size_t)tok * D, pb = (size_t)s * D, xb = (size_t)rowi * D;
  float vloc[4]; float ss = 0.f;
  #pragma unroll
  for (int q = 0; q < 4; ++q) {
    int d = threadIdx.x + q * 256;
    float v = emb[eb + d] + pos[pb + d];
    vloc[q] = v; ss += v * v;
  }
  ss = block_sum256(ss);
  float r = 1.f / fmaxf(sqrtf(ss), 1e-12f);
  #pragma unroll
  for (int q = 0; q < 4; ++q) {
    int d = threadIdx.x + q * 256;
    float v = vloc[q] * r;
    x[xb + d] = v;
    x16[xb + d] = (_Float16)v;
  }
}

__global__ __launch_bounds__(256) void final_norm(
    const float* __restrict__ x, const float* __restrict__ w,
    _Float16* __restrict__ xf, int D)
{
  const size_t base = (size_t)blockIdx.x * D;
  float s1 = 0.f, s2 = 0.f;
  float vloc[4], wloc[4];
  #pragma unroll
  for (int q = 0; q < 4; ++q) {
    int d = threadIdx.x + q * 256;
    float v = x[base + d], ww = w[d];
    vloc[q] = v; wloc[q] = ww;
    s1 += v * v; s2 += v * ww * v * ww;
  }
  s1 = block_sum256(s1);
  s2 = block_sum256(s2);
  float r1 = 1.f / sqrtf(s1 / D + 1e-8f);
  float m2 = r1 * r1 * (s2 / D);
  float r2 = 1.f / sqrtf(m2 + 1e-8f);
  float sc = r1 * r2 * 0.8f;
  #pragma unroll
  for (int q = 0; q < 4; ++q) {
    int d = threadIdx.x + q * 256;
    xf[base + d] = (_Float16)(vloc[q] * wloc[q] * sc);
  }
}

__global__ __launch_bounds__(256) void fix_row(
    float* __restrict__ out, const float* __restrict__ psum,
    const float* __restrict__ psq, int PW, int V)
{
  const int row = blockIdx.x;
  float s = 0.f, q = 0.f;
  for (int j = threadIdx.x; j < PW; j += 256) {
    s += psum[(size_t)row * PW + j];
    q += psq [(size_t)row * PW + j];
  }
  s = block_sum256(s);
  q = block_sum256(q);
  float mean = s / V;
  float var = (q - (float)V * mean * mean) / (float)(V - 1);
  var = fmaxf(var, 0.f);
  const float sc = 1.f / fmaxf(sqrtf(var), 1.f);
  float* rowp = out + (size_t)row * V;
  for (int j = threadIdx.x * 4; j < V; j += 1024) {
    f32x4 v = *(f32x4*)&rowp[j];
    #pragma unroll
    for (int t = 0; t < 4; ++t)
      v[t] = fminf(fmaxf(v[t] * sc, -10.f), 10.f);
    *(f32x4*)&rowp[j] = v;
  }
}

__global__ void tsplit16(const float* __restrict__ W, _Float16* __restrict__ WT,
                         int K, int N)
{
  __shared__ float t[32][33];
  const size_t bo = (size_t)blockIdx.z * K * N;
  const int tx = threadIdx.x, ty = threadIdx.y;
  #pragma unroll
  for (int i = 0; i < 32; i += 8) {
    int kk = blockIdx.y * 32 + ty + i;
    int nn = blockIdx.x * 32 + tx;
    t[ty + i][tx] = W[bo + (size_t)kk * N + nn];
  }
  __syncthreads();
  #pragma unroll
  for (int i = 0; i < 32; i += 8) {
    int nn = blockIdx.x * 32 + ty + i;
    int kk = blockIdx.y * 32 + tx;
    WT[bo + (size_t)nn * K + kk] = (_Float16)t[tx][ty + i];
  }
}

__global__ void cvt_f16(const float* __restrict__ in, _Float16* __restrict__ o, size_t n)
{
  for (size_t i = (size_t)blockIdx.x * 256 + threadIdx.x; i < n;
       i += (size_t)gridDim.x * 256)
    o[i] = (_Float16)in[i];
}

// ---------------------------------------------------------------------------
extern "C" void kernel_launch(void* const* d_in, const int* in_sizes, int n_in,
                              void* d_out, int out_size, void* d_ws, size_t ws_size,
                              hipStream_t stream)
{
  (void)in_sizes; (void)n_in; (void)out_size; (void)ws_size;
  const int*   ids = (const int*)  d_in[0];
  const float* emb = (const float*)d_in[1];
  const float* pos = (const float*)d_in[2];
  const float* kw  = (const float*)d_in[3];
  const float* cw  = (const float*)d_in[4];
  const float* cb  = (const float*)d_in[5];
  const float* w1  = (const float*)d_in[6];
  const float* b1  = (const float*)d_in[7];
  const float* w2  = (const float*)d_in[8];
  const float* b2  = (const float*)d_in[9];
  const float* nw  = (const float*)d_in[10];
  const float* pl  = (const float*)d_in[11];
  const float* fnw = (const float*)d_in[12];
  float* out = (float*)d_out;

  constexpr int B = 2, S = 1024, D = 1024, L = 8, V = 32000;
  constexpr int M = B * S;
  const size_t MN = (size_t)M * D;

  size_t off = 0;
  auto alloc = [&](size_t bytes) {
    char* p = (char*)d_ws + off;
    off += (bytes + 255) & ~(size_t)255;
    return (void*)p;
  };
  _Float16* kwT  = (_Float16*)alloc((size_t)L * 2 * D * D * 2);
  _Float16* w1T  = (_Float16*)alloc((size_t)L * 2 * D * D * 2);
  _Float16* w2T  = (_Float16*)alloc((size_t)L * 2 * D * D * 2);
  _Float16* plT  = (_Float16*)alloc((size_t)4 * D * D * 2);
  _Float16* emb16 = (_Float16*)alloc((size_t)V * D * 2);
  float* x    = (float*)alloc(MN * 4);
  _Float16* x16 = (_Float16*)alloc(MN * 2);
  float* vaT  = (float*)alloc((size_t)M * 2 * D * 4);   // [2D][M]
  float* pbig = (float*)alloc(2 * MN * 4);              // G3 split-K partials
  _Float16* z16 = (_Float16*)alloc(MN * 2);
  _Float16* u16 = (_Float16*)alloc((size_t)M * 2 * D * 2);
  _Float16* d16 = (_Float16*)alloc(MN * 2);
  _Float16* xf16 = (_Float16*)alloc(MN * 2);

  const int PW = V >> 6;                 // 500
  float* psum = vaT;                     // overlay (dead at head time)
  float* psq  = vaT + (size_t)M * PW;

  {
    dim3 tb(32, 8);
    tsplit16<<<dim3(2 * D / 32, D / 32, L), tb, 0, stream>>>(kw, kwT, D, 2 * D);
    tsplit16<<<dim3(2 * D / 32, D / 32, L), tb, 0, stream>>>(w1, w1T, D, 2 * D);
    tsplit16<<<dim3(D / 32, 2 * D / 32, L), tb, 0, stream>>>(w2, w2T, 2 * D, D);
    tsplit16<<<dim3(D / 32, D / 32, 4),     tb, 0, stream>>>(pl, plT, D, D);
    cvt_f16<<<4096, 256, 0, stream>>>(emb, emb16, (size_t)V * D);
  }

  embed_norm<<<M, 256, 0, stream>>>(ids, emb, pos, x, x16, S, D);

  for (int i = 0; i < L; ++i) {
    const _Float16* kwi = kwT + (size_t)i * 2 * D * D;
    const _Float16* w1i = w1T + (size_t)i * 2 * D * D;
    const _Float16* w2i = w2T + (size_t)i * 2 * D * D;

    // G1: vaT = act(x@kw), channel-major, fused tanh/sigm (256 blocks)
    gemm9<1, 1><<<(M / 128) * (2 * D / 128), 256, 0, stream>>>(
        x16, kwi, M, 2 * D, D, vaT, nullptr, nullptr, nullptr, nullptr, D);

    scanconv<<<B * D / 8, 256, 0, stream>>>(
        vaT, cw + (size_t)i * D * 3, cb + (size_t)i * D, z16, S, D, M);

    // G2: u = silu(z@w1 + b1) -> fp16 (256 blocks)
    gemm9<2, 1><<<(M / 128) * (2 * D / 128), 256, 0, stream>>>(
        z16, w1i, M, 2 * D, D, nullptr, u16, b1 + (size_t)i * 2 * D,
        nullptr, nullptr, 0);

    // G3: hf partials = u@w2 (split-K x2, 256 blocks)
    gemm9<5, 2><<<(M / 128) * (D / 128) * 2, 256, 0, stream>>>(
        u16, w2i, M, D, 2 * D, pbig, nullptr, nullptr, nullptr, nullptr, 0);

    const int mode = (i >= L - 4) ? 1 : 0;
    rms_fuse<<<M, 256, 0, stream>>>(pbig, b2 + (size_t)i * D, nw + (size_t)i * D,
                                    x, mode ? d16 : x16, D, mode, MN);
    if (mode) {
      const _Float16* pli = plT + (size_t)(i - 4) * D * D;
      // G4: x += delta@plastic (direct accumulate, writes x16; 128 blocks)
      gemm9<4, 1><<<(M / 128) * (D / 128), 256, 0, stream>>>(
          d16, pli, M, D, D, x, x16, nullptr, nullptr, nullptr, 0);
    }
  }

  final_norm<<<M, 256, 0, stream>>>(x, fnw, xf16, D);

  // LM head: 128^2 2-blocks/CU schedule + fused row stats (4000 blocks)
  gemm9<0, 1><<<(M / 128) * (V / 128), 256, 0, stream>>>(
      xf16, emb16, M, V, D, out, nullptr, nullptr, psum, psq, 0);

  fix_row<<<M, 256, 0, stream>>>(out, psum, psq, PW, V);
}

// Round 10
// 1134.588 us; speedup vs baseline: 1.3745x; 1.0327x over previous
//
#include <hip/hip_runtime.h>

// ---------------------------------------------------------------------------
// MRT12 v10: head GEMM = m201-style 256^2 8-phase schedule (8 waves, BK=64,
// 128KB LDS [dbuf][A/B][half], 1 half-tile staged/phase, counted vmcnt(4) at
// phases 4/8, lgkmcnt(0)+sched_barrier before each 16-MFMA cluster, setprio,
// slot^=(row&7) swizzle). Layers keep the r9 gemm9 (BK=64, held frags).
// B=2,S=1024,D=1024,L=8,V=32000. fp32 in/out.
// ---------------------------------------------------------------------------

using short8 = __attribute__((ext_vector_type(8))) short;
using half8  = __attribute__((ext_vector_type(8))) _Float16;
using f32x4  = __attribute__((ext_vector_type(4))) float;

#define DEVI __device__ __forceinline__

DEVI float sigm(float x) { return 1.0f / (1.0f + expf(-x)); }

DEVI float block_sum256(float v) {
  #pragma unroll
  for (int o = 32; o > 0; o >>= 1) v += __shfl_down(v, o, 64);
  __shared__ float sm[4];
  if ((threadIdx.x & 63) == 0) sm[threadIdx.x >> 6] = v;
  __syncthreads();
  float t = sm[0] + sm[1] + sm[2] + sm[3];
  __syncthreads();
  return t;
}

DEVI void gload16(const void* g, void* l) {    // async global->LDS, 16B/lane
  __builtin_amdgcn_global_load_lds(
      (const __attribute__((address_space(1))) unsigned*)g,
      (__attribute__((address_space(3))) unsigned*)l, 16, 0, 0);
}

// ---------------------------------------------------------------------------
// gemm10h (HEAD): C[M,N]=A[M,K]*B[N,K]^T fp16. 256x256 tile, BK=64, 8 waves
// (2Mx4N, wave 128x64). m201 8-phase schedule. Fused per-row sum/sumsq.
// ---------------------------------------------------------------------------
__global__ __launch_bounds__(512, 2) void gemm10h(
    const _Float16* __restrict__ A, const _Float16* __restrict__ B,
    int M, int N, int K,
    float* __restrict__ outF, float* __restrict__ psum, float* __restrict__ psq)
{
  // [dbuf][A=0/B=1][half][128 rows x 64 cols] ushort = 128 KB
  __shared__ __align__(16) unsigned short lds[2][2][2][128 * 64];
  const int tid  = threadIdx.x;
  const int lane = tid & 63, wid = tid >> 6;
  const int wr = wid >> 2, wc = wid & 3;        // 2 x 4 wave grid
  const int myr = lane & 15;
  const int kq  = lane >> 4;

  const int nwg  = gridDim.x;
  const int flat = blockIdx.x;
  const int swz  = (flat & 7) * (nwg >> 3) + (flat >> 3);
  const int MT   = M >> 8;
  const int m0   = (swz % MT) * 256;
  const int nt   = swz / MT;
  const int n0   = nt * 256;
  const int NT   = K / 64;                      // 16
  const int NITER = NT / 2;                     // 8

  // stage one half-tile (128 rows x 64 cols, 16KB) = 2 gloads/thread
  auto stageH = [&](int d, int arr, int h, int tileK, const _Float16* P,
                    int rowbase) {
    const int k0 = tileK * 64;
    #pragma unroll
    for (int q = 0; q < 2; ++q) {
      const int r = q * 64 + wid * 8 + (lane >> 3);     // row within half
      const int scol = ((lane & 7) ^ (r & 7)) << 3;     // pre-swizzled src
      gload16(P + (size_t)(rowbase + h * 128 + r) * K + k0 + scol,
              &lds[d][arr][h][(q * 64 + wid * 8) * 64]); // wave-uniform dest
    }
  };

  f32x4 acc[8][4] = {};
  short8 afr[2][4], bf0[2][2], bf1[2][2];

  auto readA = [&](int d, int qi) {             // 8 ds_read_b128
    #pragma unroll
    for (int kk = 0; kk < 2; ++kk)
      #pragma unroll
      for (int i = 0; i < 4; ++i) {
        const int ra = qi * 64 + i * 16 + myr;
        afr[kk][i] = *(const short8*)
            &lds[d][0][wr][ra * 64 + (((kk * 4 + kq) ^ (ra & 7)) << 3)];
      }
  };
  auto readB = [&](int d, int qj, short8 bf[2][2]) {    // 4 ds_read_b128
    #pragma unroll
    for (int kk = 0; kk < 2; ++kk)
      #pragma unroll
      for (int j = 0; j < 2; ++j) {
        const int rn = wc * 64 + qj * 32 + j * 16 + myr;
        const int h = rn >> 7, rb = rn & 127;
        bf[kk][j] = *(const short8*)
            &lds[d][1][h][rb * 64 + (((kk * 4 + kq) ^ (rb & 7)) << 3)];
      }
  };
  auto mfma16 = [&](int qi, int qj, short8 bf[2][2]) {  // one C-quadrant, K=64
    asm volatile("s_waitcnt lgkmcnt(0)" ::: "memory");
    __builtin_amdgcn_sched_barrier(0);
    __builtin_amdgcn_s_setprio(1);
    #pragma unroll
    for (int kk = 0; kk < 2; ++kk)
      #pragma unroll
      for (int i = 0; i < 4; ++i)
        #pragma unroll
        for (int j = 0; j < 2; ++j)
          acc[qi * 4 + i][qj * 2 + j] = __builtin_amdgcn_mfma_f32_16x16x32_f16(
              __builtin_bit_cast(half8, afr[kk][i]),
              __builtin_bit_cast(half8, bf[kk][j]),
              acc[qi * 4 + i][qj * 2 + j], 0, 0, 0);
    __builtin_amdgcn_s_setprio(0);
  };
  auto bar = [&] { __builtin_amdgcn_s_barrier(); asm volatile("" ::: "memory"); };

  // prologue: tile0 (buf0, 4 halves) + tile1 B (buf1); wait tile0 (vmcnt 4)
  stageH(0, 0, 0, 0, A, m0); stageH(0, 0, 1, 0, A, m0);
  stageH(0, 1, 0, 0, B, n0); stageH(0, 1, 1, 0, B, n0);
  stageH(1, 1, 0, 1, B, n0); stageH(1, 1, 1, 1, B, n0);
  asm volatile("s_waitcnt vmcnt(4)" ::: "memory");
  bar();

  for (int it = 0; it < NITER; ++it) {
    const int Tp = 2 * it + 1, Tn = 2 * it + 2, Tn1 = 2 * it + 3;
    // ---- K-tile 2it in buf0 ----
    // ph1: quad(0,0); stage Tp.A0 -> buf1
    readA(0, 0); readB(0, 0, bf0);
    stageH(1, 0, 0, Tp, A, m0);
    bar(); mfma16(0, 0, bf0); bar();
    // ph2: quad(0,1); stage Tp.A1 -> buf1
    readB(0, 1, bf1);
    stageH(1, 0, 1, Tp, A, m0);
    bar(); mfma16(0, 1, bf1); bar();
    // ph3: quad(1,1); stage Tn.B0 -> buf0 (B region free after ph2)
    readA(0, 1);
    if (Tn < NT) stageH(0, 1, 0, Tn, B, n0);
    bar(); mfma16(1, 1, bf1); bar();
    // ph4: quad(1,0); stage Tn.B1 -> buf0; counted vmcnt (Tp must be landed)
    if (Tn < NT) stageH(0, 1, 1, Tn, B, n0);
    bar(); mfma16(1, 0, bf0);
    if (it + 1 < NITER) { asm volatile("s_waitcnt vmcnt(4)" ::: "memory"); }
    else                { asm volatile("s_waitcnt vmcnt(0)" ::: "memory"); }
    bar();
    // ---- K-tile 2it+1 in buf1 ----
    // ph5: quad(0,0); stage Tn.A0 -> buf0 (A region free after ph4)
    readA(1, 0); readB(1, 0, bf0);
    if (Tn < NT) stageH(0, 0, 0, Tn, A, m0);
    bar(); mfma16(0, 0, bf0); bar();
    // ph6: quad(0,1); stage Tn.A1 -> buf0
    readB(1, 1, bf1);
    if (Tn < NT) stageH(0, 0, 1, Tn, A, m0);
    bar(); mfma16(0, 1, bf1); bar();
    // ph7: quad(1,1); stage Tn1.B0 -> buf1 (buf1 B free after ph6)
    readA(1, 1);
    if (Tn1 < NT) stageH(1, 1, 0, Tn1, B, n0);
    bar(); mfma16(1, 1, bf1); bar();
    // ph8: quad(1,0); stage Tn1.B1 -> buf1; counted vmcnt (Tn must be landed)
    if (Tn1 < NT) stageH(1, 1, 1, Tn1, B, n0);
    bar(); mfma16(1, 0, bf0);
    if (it + 1 < NITER) {
      asm volatile("s_waitcnt vmcnt(4)" ::: "memory");
      bar();
    }
  }

  // epilogue: C/D frag row=(lane>>4)*4+r, col=lane&15; row=wr*128+I*16+...,
  // col=wc*64+J*16+myr (identical to r8 — quadrant mapping folds into I,J)
  #pragma unroll
  for (int i8 = 0; i8 < 8; ++i8) {
    const int rbase = m0 + wr * 128 + i8 * 16 + (kq << 2);
    #pragma unroll
    for (int j4 = 0; j4 < 4; ++j4) {
      const int col = n0 + wc * 64 + j4 * 16 + myr;
      #pragma unroll
      for (int r = 0; r < 4; ++r)
        outF[(size_t)(rbase + r) * N + col] = acc[i8][j4][r];
    }
  }

  const int PW = N >> 6;
  const int pcol = (n0 >> 6) + wc;
  #pragma unroll
  for (int i8 = 0; i8 < 8; ++i8)
    #pragma unroll
    for (int r = 0; r < 4; ++r) {
      float s = 0.f, ss = 0.f;
      #pragma unroll
      for (int j4 = 0; j4 < 4; ++j4) {
        float v = acc[i8][j4][r];
        s += v; ss += v * v;
      }
      #pragma unroll
      for (int mk = 1; mk < 16; mk <<= 1) {
        s  += __shfl_xor(s,  mk, 64);
        ss += __shfl_xor(ss, mk, 64);
      }
      if (myr == ((i8 * 4 + r) & 15)) {
        const int row = m0 + wr * 128 + i8 * 16 + kq * 4 + r;
        psum[(size_t)row * PW + pcol] = s;
        psq [(size_t)row * PW + pcol] = ss;
      }
    }
}

// ---------------------------------------------------------------------------
// gemm9 (layers): unchanged from r9. 128x128, BK=64, 4 waves, 64KB LDS dbuf,
// counted vmcnt(8), reg-held fragments, slot^=(row&7) swizzle.
// EPI: 1 keygen->vaT chan-major +act; 2 +bias,silu,fp16; 4 x+=C; 5 partial.
// ---------------------------------------------------------------------------
template<int EPI, int KSPLIT>
__global__ __launch_bounds__(256, 2) void gemm9(
    const _Float16* __restrict__ A, const _Float16* __restrict__ B,
    int M, int N, int K,
    float* __restrict__ outF, _Float16* __restrict__ outH,
    const float* __restrict__ bias, int halfN)
{
  __shared__ __align__(16) unsigned short lds[2][2][128 * 64];   // 64 KB
  const int tid  = threadIdx.x;
  const int lane = tid & 63, wid = tid >> 6;
  const int wr = wid >> 1, wc = wid & 1;
  const int myr = lane & 15;
  const int kq  = lane >> 4;

  const int nwg  = gridDim.x;
  const int flat = blockIdx.x;
  const int swz  = (flat & 7) * (nwg >> 3) + (flat >> 3);
  const int ks   = (KSPLIT > 1) ? (swz % KSPLIT) : 0;
  const int tile = (KSPLIT > 1) ? (swz / KSPLIT) : swz;
  const int MT   = M >> 7;
  const int m0   = (tile % MT) * 128;
  const int n0   = (tile / MT) * 128;
  const int Kc   = K / KSPLIT;
  const int kbase = ks * Kc;
  const int NT   = Kc / 64;

  auto stage = [&](int b, int k0) {
    #pragma unroll
    for (int q = 0; q < 4; ++q) {
      const int row  = q * 32 + wid * 8 + (lane >> 3);
      const int scol = ((lane & 7) ^ (row & 7)) << 3;
      const int lb   = (q * 32 + wid * 8) * 64;
      gload16(A + (size_t)(m0 + row) * K + k0 + scol, &lds[b][0][lb]);
      gload16(B + (size_t)(n0 + row) * K + k0 + scol, &lds[b][1][lb]);
    }
  };

  f32x4 acc[4][4] = {};

  stage(0, kbase);
  stage(1, kbase + 64);
  for (int t = 0; t < NT; ++t) {
    const int b = t & 1;
    if (t + 1 < NT) { asm volatile("s_waitcnt vmcnt(8)" ::: "memory"); }
    else            { asm volatile("s_waitcnt vmcnt(0)" ::: "memory"); }
    __builtin_amdgcn_s_barrier();
    asm volatile("" ::: "memory");

    #pragma unroll
    for (int kk = 0; kk < 2; ++kk) {
      short8 af[4], bf[4];
      #pragma unroll
      for (int i = 0; i < 4; ++i) {
        const int ra = wr * 64 + i * 16 + myr;
        af[i] = *(const short8*)&lds[b][0][ra * 64 + (((kk * 4 + kq) ^ (ra & 7)) << 3)];
      }
      #pragma unroll
      for (int j = 0; j < 4; ++j) {
        const int rb = wc * 64 + j * 16 + myr;
        bf[j] = *(const short8*)&lds[b][1][rb * 64 + (((kk * 4 + kq) ^ (rb & 7)) << 3)];
      }
      asm volatile("s_waitcnt lgkmcnt(0)" ::: "memory");
      if (kk == 1) {
        __builtin_amdgcn_s_barrier();
        asm volatile("" ::: "memory");
        if (t + 2 < NT) stage(b, kbase + (t + 2) * 64);
      }
      __builtin_amdgcn_sched_barrier(0);
      __builtin_amdgcn_s_setprio(1);
      #pragma unroll
      for (int i = 0; i < 4; ++i)
        #pragma unroll
        for (int j = 0; j < 4; ++j)
          acc[i][j] = __builtin_amdgcn_mfma_f32_16x16x32_f16(
              __builtin_bit_cast(half8, af[i]), __builtin_bit_cast(half8, bf[j]),
              acc[i][j], 0, 0, 0);
      __builtin_amdgcn_s_setprio(0);
    }
  }

  const size_t MN = (size_t)M * N;
  #pragma unroll
  for (int i = 0; i < 4; ++i) {
    const int rbase = m0 + wr * 64 + i * 16 + (kq << 2);
    #pragma unroll
    for (int j = 0; j < 4; ++j) {
      const int col = n0 + wc * 64 + j * 16 + myr;
      if constexpr (EPI == 1) {
        f32x4 v;
        #pragma unroll
        for (int r = 0; r < 4; ++r) {
          float c = acc[i][j][r];
          v[r] = (col < halfN) ? (tanhf(c) * 3.14159265358979323846f) : sigm(c);
        }
        *(f32x4*)&outF[(size_t)col * M + rbase] = v;
      } else {
        #pragma unroll
        for (int r = 0; r < 4; ++r) {
          float c = acc[i][j][r];
          const size_t idx = (size_t)(rbase + r) * N + col;
          if constexpr (EPI == 2) {
            c += bias[col];
            outH[idx] = (_Float16)(c * sigm(c));
          } else if constexpr (EPI == 4) {
            float xn = outF[idx] + c;
            outF[idx] = xn;
            outH[idx] = (_Float16)xn;
          } else if constexpr (EPI == 5) {
            outF[(size_t)ks * MN + idx] = c;
          }
        }
      }
    }
  }
}

// ---------------------------------------------------------------------------
// Fused lerp-scan + causal dwconv3 (unchanged from r9).
// ---------------------------------------------------------------------------
__global__ __launch_bounds__(256) void scanconv(
    const float* __restrict__ vaT, const float* __restrict__ cw,
    const float* __restrict__ cb, _Float16* __restrict__ z16,
    int S, int D, int M)
{
  const int dl = threadIdx.x & 7;
  const int c  = threadIdx.x >> 3;
  const int ch = blockIdx.x * 8 + dl;
  const int b = ch >> 10, d = ch & 1023;
  const float* vrow = vaT + (size_t)d * M + b * S;
  const float* arow = vaT + (size_t)(D + d) * M + b * S;
  const int s0 = c * 32;

  f32x4 vr[8], ar[8];
  float A = 1.f, Bv = 0.f, Apm = 1.f, Bpm = 0.f;
  #pragma unroll
  for (int t = 0; t < 8; ++t) {
    vr[t] = *(const f32x4*)&vrow[s0 + t * 4];
    ar[t] = *(const f32x4*)&arow[s0 + t * 4];
    #pragma unroll
    for (int r = 0; r < 4; ++r) {
      if (t * 4 + r == 31) { Apm = A; Bpm = Bv; }
      float na = 1.f - ar[t][r];
      A *= na;
      Bv = Bv * na + ar[t][r] * vr[t][r];
    }
  }
  __shared__ float Asm[32][9], Bsm[32][9], Aps[32][9], Bps[32][9];
  Asm[c][dl] = A; Bsm[c][dl] = Bv; Aps[c][dl] = Apm; Bps[c][dl] = Bpm;
  __syncthreads();
  if (threadIdx.x < 8) {
    float run = 0.f;
    for (int cc = 0; cc < 32; ++cc) {
      float A_ = Asm[cc][dl], B_ = Bsm[cc][dl];
      Bsm[cc][dl] = run;
      run = A_ * run + B_;
    }
  }
  __syncthreads();
  float hm1 = Bsm[c][dl];
  float hm2 = (c == 0) ? 0.f
            : (Aps[c - 1][dl] * Bsm[c - 1][dl] + Bps[c - 1][dl]);

  const float w0 = cw[d * 3 + 0], w1 = cw[d * 3 + 1], w2 = cw[d * 3 + 2];
  const float bc = cb[d];
  #pragma unroll
  for (int t = 0; t < 8; ++t) {
    #pragma unroll
    for (int r = 0; r < 4; ++r) {
      float h = hm1 + ar[t][r] * (vr[t][r] - hm1);
      float z = h + bc + w0 * hm2 + w1 * hm1 + w2 * h;
      z16[(size_t)(b * S + s0 + t * 4 + r) * D + d] = (_Float16)z;
      hm2 = hm1; hm1 = h;
    }
  }
}

__global__ __launch_bounds__(256) void rms_fuse(
    const float* __restrict__ p, const float* __restrict__ bias,
    const float* __restrict__ nw, float* __restrict__ x,
    _Float16* __restrict__ o16, int D, int mode, size_t MN)
{
  const size_t base = (size_t)blockIdx.x * D;
  float vloc[4]; float ss = 0.f;
  #pragma unroll
  for (int q = 0; q < 4; ++q) {
    int d = threadIdx.x + q * 256;
    float v = p[base + d] + p[MN + base + d] + bias[d];
    vloc[q] = v; ss += v * v;
  }
  ss = block_sum256(ss);
  float r = 1.f / sqrtf(ss / D + 1e-8f);
  #pragma unroll
  for (int q = 0; q < 4; ++q) {
    int d = threadIdx.x + q * 256;
    float delta = vloc[q] * r * nw[d];
    float xn = x[base + d] + delta;
    x[base + d] = xn;
    o16[base + d] = (_Float16)(mode ? delta : xn);
  }
}

__global__ __launch_bounds__(256) void embed_norm(
    const int* __restrict__ ids, const float* __restrict__ emb,
    const float* __restrict__ pos,
    float* __restrict__ x, _Float16* __restrict__ x16, int S, int D)
{
  const int rowi = blockIdx.x;
  const int s = rowi % S;
  const int tok = ids[rowi];
  const size_t eb = (size_t)tok * D, pb = (size_t)s * D, xb = (size_t)rowi * D;
  float vloc[4]; float ss = 0.f;
  #pragma unroll
  for (int q = 0; q < 4; ++q) {
    int d = threadIdx.x + q * 256;
    float v = emb[eb + d] + pos[pb + d];
    vloc[q] = v; ss += v * v;
  }
  ss = block_sum256(ss);
  float r = 1.f / fmaxf(sqrtf(ss), 1e-12f);
  #pragma unroll
  for (int q = 0; q < 4; ++q) {
    int d = threadIdx.x + q * 256;
    float v = vloc[q] * r;
    x[xb + d] = v;
    x16[xb + d] = (_Float16)v;
  }
}

__global__ __launch_bounds__(256) void final_norm(
    const float* __restrict__ x, const float* __restrict__ w,
    _Float16* __restrict__ xf, int D)
{
  const size_t base = (size_t)blockIdx.x * D;
  float s1 = 0.f, s2 = 0.f;
  float vloc[4], wloc[4];
  #pragma unroll
  for (int q = 0; q < 4; ++q) {
    int d = threadIdx.x + q * 256;
    float v = x[base + d], ww = w[d];
    vloc[q] = v; wloc[q] = ww;
    s1 += v * v; s2 += v * ww * v * ww;
  }
  s1 = block_sum256(s1);
  s2 = block_sum256(s2);
  float r1 = 1.f / sqrtf(s1 / D + 1e-8f);
  float m2 = r1 * r1 * (s2 / D);
  float r2 = 1.f / sqrtf(m2 + 1e-8f);
  float sc = r1 * r2 * 0.8f;
  #pragma unroll
  for (int q = 0; q < 4; ++q) {
    int d = threadIdx.x + q * 256;
    xf[base + d] = (_Float16)(vloc[q] * wloc[q] * sc);
  }
}

__global__ __launch_bounds__(256) void fix_row(
    float* __restrict__ out, const float* __restrict__ psum,
    const float* __restrict__ psq, int PW, int V)
{
  const int row = blockIdx.x;
  float s = 0.f, q = 0.f;
  for (int j = threadIdx.x; j < PW; j += 256) {
    s += psum[(size_t)row * PW + j];
    q += psq [(size_t)row * PW + j];
  }
  s = block_sum256(s);
  q = block_sum256(q);
  float mean = s / V;
  float var = (q - (float)V * mean * mean) / (float)(V - 1);
  var = fmaxf(var, 0.f);
  const float sc = 1.f / fmaxf(sqrtf(var), 1.f);
  float* rowp = out + (size_t)row * V;
  for (int j = threadIdx.x * 4; j < V; j += 1024) {
    f32x4 v = *(f32x4*)&rowp[j];
    #pragma unroll
    for (int t = 0; t < 4; ++t)
      v[t] = fminf(fmaxf(v[t] * sc, -10.f), 10.f);
    *(f32x4*)&rowp[j] = v;
  }
}

__global__ void tsplit16(const float* __restrict__ W, _Float16* __restrict__ WT,
                         int K, int N)
{
  __shared__ float t[32][33];
  const size_t bo = (size_t)blockIdx.z * K * N;
  const int tx = threadIdx.x, ty = threadIdx.y;
  #pragma unroll
  for (int i = 0; i < 32; i += 8) {
    int kk = blockIdx.y * 32 + ty + i;
    int nn = blockIdx.x * 32 + tx;
    t[ty + i][tx] = W[bo + (size_t)kk * N + nn];
  }
  __syncthreads();
  #pragma unroll
  for (int i = 0; i < 32; i += 8) {
    int nn = blockIdx.x * 32 + ty + i;
    int kk = blockIdx.y * 32 + tx;
    WT[bo + (size_t)nn * K + kk] = (_Float16)t[tx][ty + i];
  }
}

__global__ void cvt_f16(const float* __restrict__ in, _Float16* __restrict__ o, size_t n)
{
  for (size_t i = (size_t)blockIdx.x * 256 + threadIdx.x; i < n;
       i += (size_t)gridDim.x * 256)
    o[i] = (_Float16)in[i];
}

// ---------------------------------------------------------------------------
extern "C" void kernel_launch(void* const* d_in, const int* in_sizes, int n_in,
                              void* d_out, int out_size, void* d_ws, size_t ws_size,
                              hipStream_t stream)
{
  (void)in_sizes; (void)n_in; (void)out_size; (void)ws_size;
  const int*   ids = (const int*)  d_in[0];
  const float* emb = (const float*)d_in[1];
  const float* pos = (const float*)d_in[2];
  const float* kw  = (const float*)d_in[3];
  const float* cw  = (const float*)d_in[4];
  const float* cb  = (const float*)d_in[5];
  const float* w1  = (const float*)d_in[6];
  const float* b1  = (const float*)d_in[7];
  const float* w2  = (const float*)d_in[8];
  const float* b2  = (const float*)d_in[9];
  const float* nw  = (const float*)d_in[10];
  const float* pl  = (const float*)d_in[11];
  const float* fnw = (const float*)d_in[12];
  float* out = (float*)d_out;

  constexpr int B = 2, S = 1024, D = 1024, L = 8, V = 32000;
  constexpr int M = B * S;
  const size_t MN = (size_t)M * D;

  size_t off = 0;
  auto alloc = [&](size_t bytes) {
    char* p = (char*)d_ws + off;
    off += (bytes + 255) & ~(size_t)255;
    return (void*)p;
  };
  _Float16* kwT  = (_Float16*)alloc((size_t)L * 2 * D * D * 2);
  _Float16* w1T  = (_Float16*)alloc((size_t)L * 2 * D * D * 2);
  _Float16* w2T  = (_Float16*)alloc((size_t)L * 2 * D * D * 2);
  _Float16* plT  = (_Float16*)alloc((size_t)4 * D * D * 2);
  _Float16* emb16 = (_Float16*)alloc((size_t)V * D * 2);
  float* x    = (float*)alloc(MN * 4);
  _Float16* x16 = (_Float16*)alloc(MN * 2);
  float* vaT  = (float*)alloc((size_t)M * 2 * D * 4);   // [2D][M]
  float* pbig = (float*)alloc(2 * MN * 4);              // G3 split-K partials
  _Float16* z16 = (_Float16*)alloc(MN * 2);
  _Float16* u16 = (_Float16*)alloc((size_t)M * 2 * D * 2);
  _Float16* d16 = (_Float16*)alloc(MN * 2);
  _Float16* xf16 = (_Float16*)alloc(MN * 2);

  const int PW = V >> 6;                 // 500
  float* psum = vaT;                     // overlay (dead at head time)
  float* psq  = vaT + (size_t)M * PW;

  {
    dim3 tb(32, 8);
    tsplit16<<<dim3(2 * D / 32, D / 32, L), tb, 0, stream>>>(kw, kwT, D, 2 * D);
    tsplit16<<<dim3(2 * D / 32, D / 32, L), tb, 0, stream>>>(w1, w1T, D, 2 * D);
    tsplit16<<<dim3(D / 32, 2 * D / 32, L), tb, 0, stream>>>(w2, w2T, 2 * D, D);
    tsplit16<<<dim3(D / 32, D / 32, 4),     tb, 0, stream>>>(pl, plT, D, D);
    cvt_f16<<<4096, 256, 0, stream>>>(emb, emb16, (size_t)V * D);
  }

  embed_norm<<<M, 256, 0, stream>>>(ids, emb, pos, x, x16, S, D);

  for (int i = 0; i < L; ++i) {
    const _Float16* kwi = kwT + (size_t)i * 2 * D * D;
    const _Float16* w1i = w1T + (size_t)i * 2 * D * D;
    const _Float16* w2i = w2T + (size_t)i * 2 * D * D;

    // G1: vaT = act(x@kw), channel-major, fused tanh/sigm
    gemm9<1, 1><<<(M / 128) * (2 * D / 128), 256, 0, stream>>>(
        x16, kwi, M, 2 * D, D, vaT, nullptr, nullptr, D);

    scanconv<<<B * D / 8, 256, 0, stream>>>(
        vaT, cw + (size_t)i * D * 3, cb + (size_t)i * D, z16, S, D, M);

    // G2: u = silu(z@w1 + b1) -> fp16
    gemm9<2, 1><<<(M / 128) * (2 * D / 128), 256, 0, stream>>>(
        z16, w1i, M, 2 * D, D, nullptr, u16, b1 + (size_t)i * 2 * D, 0);

    // G3: hf partials = u@w2 (split-K x2)
    gemm9<5, 2><<<(M / 128) * (D / 128) * 2, 256, 0, stream>>>(
        u16, w2i, M, D, 2 * D, pbig, nullptr, nullptr, 0);

    const int mode = (i >= L - 4) ? 1 : 0;
    rms_fuse<<<M, 256, 0, stream>>>(pbig, b2 + (size_t)i * D, nw + (size_t)i * D,
                                    x, mode ? d16 : x16, D, mode, MN);
    if (mode) {
      const _Float16* pli = plT + (size_t)(i - 4) * D * D;
      // G4: x += delta@plastic (direct accumulate, writes x16)
      gemm9<4, 1><<<(M / 128) * (D / 128), 256, 0, stream>>>(
          d16, pli, M, D, D, x, x16, nullptr, 0);
    }
  }

  final_norm<<<M, 256, 0, stream>>>(x, fnw, xf16, D);

  // LM head: 256^2 8-phase schedule + fused row stats (1000 blocks)
  gemm10h<<<(M / 256) * (V / 256), 512, 0, stream>>>(
      xf16, emb16, M, V, D, out, psum, psq);

  fix_row<<<M, 256, 0, stream>>>(out, psum, psq, PW, V);
}